// Round 3
// baseline (366.331 us; speedup 1.0000x reference)
//
#include <hip/hip_runtime.h>
#include <hip/hip_bf16.h>

// ---------------------------------------------------------------------------
// GraphSAGE 3-layer encoder, fp32 in/out.
//   per layer: h_out = relu?( mean_agg(h)@Wl + b + h@Wr )
// Identity: segment_sum(h[src])@Wl == segment_sum((h@Wl)[src])
//   -> project first (MFMA bf16), aggregate small vectors via CSR gather.
// R9 -> R10:
//   * R7/R8/R9 post-mortem: register x double-buffer (64 VGPR) is the poison.
//     At VGPR_Count=64 total it can't be live -> compiler serializes
//     load->consume; per-wave MLP collapses; BW stuck at 2.3 TB/s.
//   * R10 proj1: x tiles staged into LDS via global_load_lds (16B async DMA,
//     zero VGPR cost). 32-row tiles double-buffered (32 KB) + 16 KB weights
//     = 48 KB, 3 blocks/CU. 2-phase loop: issue STAGE(t+1), compute(t),
//     one barrier (drains vmcnt). In-flight bytes now come from DMA depth.
//   * ch-pair blocks (b, b^8) now land on the SAME XCD (ch=(b>>3)&1) so the
//     duplicated x read of a pair hits that XCD's L2 (R9: FETCH 76->100 MB
//     because pairs were on different XCDs).
//   * proj2/proj3 (bf16-in, small) keep the R9 register path.
// ---------------------------------------------------------------------------

typedef __attribute__((ext_vector_type(8))) short short8;
typedef __attribute__((ext_vector_type(4))) float f32x4;

__device__ inline unsigned short f2b(float x) {
    return __bfloat16_as_ushort(__float2bfloat16(x));
}
__device__ inline float b2f(unsigned short u) {
    return __uint_as_float(((unsigned)u) << 16);
}

__device__ __forceinline__ void gload_lds16(const void* g, void* l) {
    __builtin_amdgcn_global_load_lds(
        (const __attribute__((address_space(1))) void*)g,
        (__attribute__((address_space(3))) void*)l, 16, 0, 0);
}

// ============================ CSR construction =============================

__global__ void zero_ints(int* __restrict__ p, int n) {
    int i = blockIdx.x * blockDim.x + threadIdx.x;
    if (i < n) p[i] = 0;
}

__global__ void hist_kernel(const int* __restrict__ dst, int* __restrict__ deg, int E) {
    int i = blockIdx.x * blockDim.x + threadIdx.x;
    if (i < E) atomicAdd(&deg[dst[i]], 1);
}

__global__ void scan_reduce(const int* __restrict__ deg, int* __restrict__ bsum, int n) {
    __shared__ int s[256];
    int i = blockIdx.x * 256 + threadIdx.x;
    s[threadIdx.x] = (i < n) ? deg[i] : 0;
    __syncthreads();
    for (int off = 128; off > 0; off >>= 1) {
        if (threadIdx.x < off) s[threadIdx.x] += s[threadIdx.x + off];
        __syncthreads();
    }
    if (threadIdx.x == 0) bsum[blockIdx.x] = s[0];
}

__global__ void scan_top(int* __restrict__ bsum, int nb) {
    __shared__ int s[1024];
    int t = threadIdx.x;
    int v = (t < nb) ? bsum[t] : 0;
    s[t] = v;
    __syncthreads();
    for (int off = 1; off < 1024; off <<= 1) {
        int add = (t >= off) ? s[t - off] : 0;
        __syncthreads();
        s[t] += add;
        __syncthreads();
    }
    if (t < nb) bsum[t] = s[t] - v;  // exclusive
}

__global__ void scan_final(const int* __restrict__ deg, const int* __restrict__ bsum,
                           int* __restrict__ rowptr, int* __restrict__ cursor,
                           int n, int E) {
    __shared__ int s[256];
    int t = threadIdx.x;
    int i = blockIdx.x * 256 + t;
    int v = (i < n) ? deg[i] : 0;
    s[t] = v;
    __syncthreads();
    for (int off = 1; off < 256; off <<= 1) {
        int add = (t >= off) ? s[t - off] : 0;
        __syncthreads();
        s[t] += add;
        __syncthreads();
    }
    int excl = s[t] - v + bsum[blockIdx.x];
    if (i < n) {
        rowptr[i] = excl;
        cursor[i] = excl;
    }
    if (i == 0) rowptr[n] = E;
}

__global__ void fill_kernel(const int* __restrict__ src, const int* __restrict__ dst,
                            int* __restrict__ cursor, int* __restrict__ csr, int E) {
    int e = blockIdx.x * blockDim.x + threadIdx.x;
    if (e < E) {
        int pos = atomicAdd(&cursor[dst[e]], 1);
        csr[pos] = src[e];
    }
}

// ====================== layer-1 MFMA projection (LDS x) ====================
// 128 -> (64|64). p = x@Wl ; r = x@Wr + b. Weight cols concatenated
// [0,64)->p, [64,128)->r. CH=2 block col-split: ch = (b>>3)&1 so the two
// blocks of a pair (b, b^8) sit on the SAME XCD; each stages 16 KB of
// weight fragments (proven conflict-free fragment order, R6-R9).
// x: 32-row fp32 tiles, double-buffered in LDS via global_load_lds (16B).
// Waves: 2 row-groups x 2 col-groups. A-fragments built per k-step from
// 2x ds_read_b128 + 8 cvt (transient regs only).
// MFMA 16x16x32: A[m=lane&15][k=(lane>>4)*8+i]; D col=lane&15,
// row=(lane>>4)*4+reg (verified R3-R6).

__launch_bounds__(256, 4)
__global__ void proj1_mfma(const float* __restrict__ x,
                           const float* __restrict__ Wl,
                           const float* __restrict__ Wr,
                           const float* __restrict__ bl,
                           unsigned short* __restrict__ pv,
                           unsigned short* __restrict__ rv,
                           int n) {
    constexpr int S = 4;             // k-steps (128/32)
    constexpr int TWB = 4;           // weight col-tiles staged per block
    constexpr int NCH = TWB * S * 64;

    __shared__ unsigned short sW[NCH * 8];   // 16 KB
    __shared__ float sX[2][32 * 128];        // 2 x 16 KB

    const int b = (int)blockIdx.x;
    const int ch = (b >> 3) & 1;
    const int blk = (b & 7) | ((b >> 4) << 3);
    const int nblk = (int)gridDim.x >> 1;

    const int tid = threadIdx.x;
    // stage this block's ch-half of weights as lane-ordered fragments
    for (int chunk = tid; chunk < NCH; chunk += 256) {
        const int lane_c = chunk & 63;
        const int rest = chunk >> 6;         // t*S + s
        const int s = rest % S;
        const int t = rest / S;
        const int c = (ch * TWB + t) * 16 + (lane_c & 15);
        const int k0 = s * 32 + (lane_c >> 4) * 8;
        short8 pack;
#pragma unroll
        for (int j = 0; j < 8; ++j) {
            const int k = k0 + j;
            float w = (c < 64) ? Wl[k * 64 + c] : Wr[k * 64 + (c - 64)];
            pack[j] = (short)f2b(w);
        }
        *reinterpret_cast<short8*>(&sW[(size_t)chunk * 8]) = pack;
    }

    const int wave = tid >> 6, lane = tid & 63;
    const int rg = wave & 1, cw = wave >> 1;   // row-group, col-group
    const int q = lane >> 4, ln = lane & 15;

    int colg[2];
    float bias[2];
#pragma unroll
    for (int t = 0; t < 2; ++t) {
        colg[t] = ch * 64 + (cw * 2 + t) * 16 + ln;
        bias[t] = (colg[t] >= 64) ? bl[colg[t] - 64] : 0.0f;
    }

    // async-stage one 32-row x tile into sX[d] (1024 x 16B chunks)
    auto stage = [&](int d, int nb) {
#pragma unroll
        for (int i = 0; i < 4; ++i) {
            const int cbase = wave * 256 + i * 64;       // wave-uniform
            const int ci = cbase + lane;
            int row = nb + (ci >> 5);
            if (row >= n) row = n - 1;                   // clamp (stores guarded)
            const float* g = x + (size_t)row * 128 + (ci & 31) * 4;
            char* l = (char*)&sX[d][0] + (size_t)cbase * 16;
            gload_lds16(g, l);
        }
    };

    auto compute = [&](int d, int nb) {
        const int rowb = nb + rg * 16;
        f32x4 acc0 = (f32x4){0.f, 0.f, 0.f, 0.f};
        f32x4 acc1 = (f32x4){0.f, 0.f, 0.f, 0.f};
        const int bt = cw * 2;
#pragma unroll
        for (int s = 0; s < S; ++s) {
            const float* xr = &sX[d][(rg * 16 + ln) * 128 + s * 32 + q * 8];
            float4 v0 = *reinterpret_cast<const float4*>(xr);
            float4 v1 = *reinterpret_cast<const float4*>(xr + 4);
            short8 a;
            a[0] = (short)f2b(v0.x); a[1] = (short)f2b(v0.y);
            a[2] = (short)f2b(v0.z); a[3] = (short)f2b(v0.w);
            a[4] = (short)f2b(v1.x); a[5] = (short)f2b(v1.y);
            a[6] = (short)f2b(v1.z); a[7] = (short)f2b(v1.w);
            short8 bf0 = *reinterpret_cast<const short8*>(
                &sW[((size_t)(bt * S + s)) * 512 + (size_t)lane * 8]);
            short8 bf1 = *reinterpret_cast<const short8*>(
                &sW[((size_t)((bt + 1) * S + s)) * 512 + (size_t)lane * 8]);
            acc0 = __builtin_amdgcn_mfma_f32_16x16x32_bf16(a, bf0, acc0, 0, 0, 0);
            acc1 = __builtin_amdgcn_mfma_f32_16x16x32_bf16(a, bf1, acc1, 0, 0, 0);
        }
#pragma unroll
        for (int t = 0; t < 2; ++t) {
            const f32x4 acc = t ? acc1 : acc0;
            const int c = colg[t];
#pragma unroll
            for (int rr = 0; rr < 4; ++rr) {
                const int row = rowb + q * 4 + rr;
                if (row < n) {
                    if (c < 64)
                        pv[(size_t)row * 64 + c] = f2b(acc[rr]);
                    else
                        rv[(size_t)row * 64 + (c - 64)] = f2b(acc[rr] + bias[t]);
                }
            }
        }
    };

    constexpr int npi = 32;
    const int stride = nblk * npi;
    int nb = blk * npi;
    if (nb >= n) return;
    stage(0, nb);
    __syncthreads();          // weights + tile0 ready
    while (true) {
        const int nb1 = nb + stride;
        if (nb1 < n) stage(1, nb1);
        compute(0, nb);
        __syncthreads();      // tile1 arrived; sX[0] free
        if (nb1 >= n) break;
        const int nb2 = nb1 + stride;
        if (nb2 < n) stage(0, nb2);
        compute(1, nb1);
        __syncthreads();
        nb = nb2;
        if (nb >= n) break;
    }
}

// ==================== layers 2/3 MFMA projection (regs) ====================
// bf16 input, small rows; R9 register path (VGPR<=64, works).

template <int DIN, int DP, int DR, int DT2, int CH, int NU,
          bool RELU, bool IN_BF16, bool OUT_BF16>
__launch_bounds__(256, 4)
__global__ void proj_mfma(const void* __restrict__ xv,
                          const float* __restrict__ Wl,
                          const float* __restrict__ Wr,
                          const float* __restrict__ bl,
                          void* __restrict__ pv,
                          void* __restrict__ rv,
                          int n) {
    constexpr int WAVES = 4;             // 256 threads
    constexpr int TILES = DT2 / 16;
    constexpr int TW = TILES / CH;       // col tiles per block (= per wave)
    constexpr int S = DIN / 32;          // MFMA k-steps
    constexpr int NCH = TW * S * 64;     // 16B fragment chunks staged/block

    __shared__ unsigned short sF[NCH * 8];

    const int ch   = (CH > 1) ? ((int)blockIdx.x % CH) : 0;
    const int blk  = (int)blockIdx.x / CH;
    const int nblk = (int)gridDim.x / CH;

    const int tid = threadIdx.x;
    // stage this block's ch-part of weights as lane-ordered fragments
    for (int chunk = tid; chunk < NCH; chunk += 256) {
        const int lane_c = chunk & 63;
        const int rest = chunk >> 6;         // t*S + s
        const int s = rest % S;
        const int t = rest / S;
        const int c = (ch * TW + t) * 16 + (lane_c & 15);
        const int k0 = s * 32 + (lane_c >> 4) * 8;
        short8 pack;
#pragma unroll
        for (int j = 0; j < 8; ++j) {
            float w = 0.f;
            const int k = k0 + j;
            if (c < DP) w = Wl[k * DP + c];
            else if (c < DP + DR) w = Wr[k * DR + (c - DP)];
            pack[j] = (short)f2b(w);
        }
        *reinterpret_cast<short8*>(&sF[(size_t)chunk * 8]) = pack;
    }
    __syncthreads();

    const int wave = tid >> 6, lane = tid & 63;
    const int ng = wave;                 // all waves in block share ch
    const int q = lane >> 4, ln = lane & 15;
    const int colbase = ch * (TW * 16);

    // lane's fragment base: frag (t,s) at +(t*S+s)*512 ushorts
    const unsigned short* fbase = &sF[(size_t)lane * 8];

    int colg[TW];
    float bias[TW];
#pragma unroll
    for (int t = 0; t < TW; ++t) {
        colg[t] = colbase + t * 16 + ln;
        bias[t] = (colg[t] >= DP && colg[t] < DP + DR) ? bl[colg[t] - DP] : 0.0f;
    }

    // raw-x double buffers (unused dtype pair is DCE'd)
    float4 rf0[NU][2 * S], rf1[NU][2 * S];
    short8 rb0[NU][S], rb1[NU][S];

    auto load_groups = [&](float4 (&rf)[NU][2 * S], short8 (&rb)[NU][S], int nbase) {
#pragma unroll
        for (int g = 0; g < NU; ++g) {
            const int base = nbase + (ng * NU + g) * 16;
            if (base >= n) continue;  // wave-uniform
            if constexpr (IN_BF16) {
                const unsigned short* xr =
                    (const unsigned short*)xv + (size_t)(base + ln) * DIN + q * 8;
#pragma unroll
                for (int s = 0; s < S; ++s)
                    rb[g][s] = *reinterpret_cast<const short8*>(xr + s * 32);
            } else {
                const float* xr = (const float*)xv + (size_t)(base + ln) * DIN + q * 8;
#pragma unroll
                for (int s = 0; s < S; ++s) {
                    rf[g][2 * s]     = *reinterpret_cast<const float4*>(xr + s * 32);
                    rf[g][2 * s + 1] = *reinterpret_cast<const float4*>(xr + s * 32 + 4);
                }
            }
        }
    };

    auto compute_groups = [&](float4 (&rf)[NU][2 * S], short8 (&rb)[NU][S], int nbase) {
#pragma unroll
        for (int g = 0; g < NU; ++g) {
            const int base = nbase + (ng * NU + g) * 16;
            if (base >= n) continue;
            short8 af[S];
#pragma unroll
            for (int s = 0; s < S; ++s) {
                if constexpr (IN_BF16) {
                    short8 a = rb[g][s];
                    if (RELU) {
#pragma unroll
                        for (int j = 0; j < 8; ++j)
                            a[j] = ((short)a[j] < 0) ? (short)0 : a[j];
                    }
                    af[s] = a;
                } else {
                    float4 v0 = rf[g][2 * s], v1 = rf[g][2 * s + 1];
                    if (RELU) {
                        v0.x = fmaxf(v0.x, 0.0f); v0.y = fmaxf(v0.y, 0.0f);
                        v0.z = fmaxf(v0.z, 0.0f); v0.w = fmaxf(v0.w, 0.0f);
                        v1.x = fmaxf(v1.x, 0.0f); v1.y = fmaxf(v1.y, 0.0f);
                        v1.z = fmaxf(v1.z, 0.0f); v1.w = fmaxf(v1.w, 0.0f);
                    }
                    short8 a;
                    a[0] = (short)f2b(v0.x); a[1] = (short)f2b(v0.y);
                    a[2] = (short)f2b(v0.z); a[3] = (short)f2b(v0.w);
                    a[4] = (short)f2b(v1.x); a[5] = (short)f2b(v1.y);
                    a[6] = (short)f2b(v1.z); a[7] = (short)f2b(v1.w);
                    af[s] = a;
                }
            }

            f32x4 acc[TW];
#pragma unroll
            for (int t = 0; t < TW; ++t) acc[t] = (f32x4){0.f, 0.f, 0.f, 0.f};
#pragma unroll
            for (int s = 0; s < S; ++s)
#pragma unroll
                for (int t = 0; t < TW; ++t) {
                    short8 bf = *reinterpret_cast<const short8*>(
                        fbase + (size_t)(t * S + s) * 512);
                    acc[t] = __builtin_amdgcn_mfma_f32_16x16x32_bf16(
                        af[s], bf, acc[t], 0, 0, 0);
                }

#pragma unroll
            for (int t = 0; t < TW; ++t) {
                const int c = colg[t];
#pragma unroll
                for (int rr = 0; rr < 4; ++rr) {
                    const int row = base + q * 4 + rr;
                    if (c < DP) {
                        if constexpr (OUT_BF16)
                            ((unsigned short*)pv)[(size_t)row * DP + c] = f2b(acc[t][rr]);
                        else
                            ((float*)pv)[(size_t)row * DP + c] = acc[t][rr];
                    } else if (c < DP + DR) {
                        const float v = acc[t][rr] + bias[t];
                        if constexpr (OUT_BF16)
                            ((unsigned short*)rv)[(size_t)row * DR + (c - DP)] = f2b(v);
                        else
                            ((float*)rv)[(size_t)row * DR + (c - DP)] = v;
                    }
                }
            }
        }
    };

    const int npi = WAVES * NU * 16;     // nodes per block-iteration
    const int stride = nblk * npi;
    int nb = blk * npi;
    if (nb >= n) return;
    load_groups(rf0, rb0, nb);
    while (true) {
        const int nb1 = nb + stride;
        if (nb1 < n) load_groups(rf1, rb1, nb1);
        compute_groups(rf0, rb0, nb);
        nb = nb1;
        if (nb >= n) break;
        const int nb2 = nb + stride;
        if (nb2 < n) load_groups(rf0, rb0, nb2);
        compute_groups(rf1, rb1, nb);
        nb = nb2;
        if (nb >= n) break;
    }
}

// ============================ aggregation ==================================
// out[d] += mean over csr row of p rows. bf16 buffers: L=D/8 lanes per node,
// one short8 per lane per gathered row; fp32 accumulation; unroll-4 keeps
// 4 independent csr->row chains in flight.

template <int D, int L>
__global__ void agg_bf16(const int* __restrict__ rowptr,
                         const int* __restrict__ csr,
                         const unsigned short* __restrict__ p,
                         unsigned short* __restrict__ out,
                         int n) {
    constexpr int RQ = D / 8;            // short8s per row
    long long gid = (long long)blockIdx.x * blockDim.x + threadIdx.x;
    int d = (int)(gid / L);
    int l = (int)(gid % L);
    if (d >= n) return;
    int beg = rowptr[d], end = rowptr[d + 1];
    int deg = end - beg;
    if (deg <= 0) return;

    const short8* pr = reinterpret_cast<const short8*>(p);
    float s[8];
#pragma unroll
    for (int j = 0; j < 8; ++j) s[j] = 0.0f;

    int i = beg;
    for (; i + 4 <= end; i += 4) {
        int e0 = csr[i], e1 = csr[i + 1], e2 = csr[i + 2], e3 = csr[i + 3];
        short8 a = pr[(size_t)e0 * RQ + l];
        short8 b = pr[(size_t)e1 * RQ + l];
        short8 c = pr[(size_t)e2 * RQ + l];
        short8 e = pr[(size_t)e3 * RQ + l];
#pragma unroll
        for (int j = 0; j < 8; ++j)
            s[j] += (b2f((unsigned short)a[j]) + b2f((unsigned short)b[j])) +
                    (b2f((unsigned short)c[j]) + b2f((unsigned short)e[j]));
    }
    for (; i < end; ++i) {
        short8 a = pr[(size_t)csr[i] * RQ + l];
#pragma unroll
        for (int j = 0; j < 8; ++j) s[j] += b2f((unsigned short)a[j]);
    }

    const float inv = 1.0f / (float)deg;
    short8* o = reinterpret_cast<short8*>(out) + (size_t)d * RQ + l;
    short8 cur = *o;
#pragma unroll
    for (int j = 0; j < 8; ++j) {
        float v = b2f((unsigned short)cur[j]) + s[j] * inv;
        cur[j] = (short)f2b(v);
    }
    *o = cur;
}

// fp32 variant for the final layer (out = d_out, fp32)
template <int D, int L>
__global__ void agg_f32(const int* __restrict__ rowptr,
                        const int* __restrict__ csr,
                        const float* __restrict__ p,
                        float* __restrict__ out,
                        int n) {
    constexpr int RQ = D / 4;            // float4s per row
    long long gid = (long long)blockIdx.x * blockDim.x + threadIdx.x;
    int d = (int)(gid / L);
    int l = (int)(gid % L);
    if (d >= n || l >= RQ) return;
    int beg = rowptr[d], end = rowptr[d + 1];
    int deg = end - beg;
    if (deg <= 0) return;

    const float4* pr = reinterpret_cast<const float4*>(p);
    float sx = 0.f, sy = 0.f, sz = 0.f, sw = 0.f;
    int i = beg;
    for (; i + 4 <= end; i += 4) {
        int s0 = csr[i], s1 = csr[i + 1], s2 = csr[i + 2], s3 = csr[i + 3];
        float4 a = pr[(size_t)s0 * RQ + l];
        float4 b = pr[(size_t)s1 * RQ + l];
        float4 c = pr[(size_t)s2 * RQ + l];
        float4 e = pr[(size_t)s3 * RQ + l];
        sx += (a.x + b.x) + (c.x + e.x);
        sy += (a.y + b.y) + (c.y + e.y);
        sz += (a.z + b.z) + (c.z + e.z);
        sw += (a.w + b.w) + (c.w + e.w);
    }
    for (; i < end; ++i) {
        float4 a = pr[(size_t)csr[i] * RQ + l];
        sx += a.x; sy += a.y; sz += a.z; sw += a.w;
    }
    const float inv = 1.0f / (float)deg;
    float4* o = reinterpret_cast<float4*>(out) + (size_t)d * RQ + l;
    float4 cur = *o;
    cur.x += sx * inv; cur.y += sy * inv;
    cur.z += sz * inv; cur.w += sw * inv;
    *o = cur;
}

// ============================ launcher =====================================

extern "C" void kernel_launch(void* const* d_in, const int* in_sizes, int n_in,
                              void* d_out, int out_size, void* d_ws, size_t ws_size,
                              hipStream_t stream) {
    const float* x   = (const float*)d_in[0];
    const int*   ei  = (const int*)d_in[1];   // (2, E) int32
    const float* Wl1 = (const float*)d_in[2];
    const float* bl1 = (const float*)d_in[3];
    const float* Wr1 = (const float*)d_in[4];
    const float* Wl2 = (const float*)d_in[5];
    const float* bl2 = (const float*)d_in[6];
    const float* Wr2 = (const float*)d_in[7];
    const float* Wl3 = (const float*)d_in[8];
    const float* bl3 = (const float*)d_in[9];
    const float* Wr3 = (const float*)d_in[10];
    float* out = (float*)d_out;

    const int N = in_sizes[0] / 128;
    const int E = in_sizes[1] / 2;
    const int* src  = ei;
    const int* dstp = ei + E;

    // workspace (bf16 intermediates):
    //   A1 bf16 N*64 | B bf16 N*64 | A2 bf16 N*32 | C bf16 N*32 |
    //   A3 f32 N*20 | rowptr (N+1) | csr (E)
    // transient CSR ints (degi, cursor, bsum) alias A3 (dead before proj3).
    unsigned short* A1 = (unsigned short*)d_ws;
    unsigned short* Bb = A1 + (size_t)N * 64;
    unsigned short* A2 = Bb + (size_t)N * 64;
    unsigned short* Cb = A2 + (size_t)N * 32;
    float* A3 = (float*)(Cb + (size_t)N * 32);
    int* rowptr = (int*)(A3 + (size_t)N * 20);
    int* csr    = rowptr + (N + 1);

    int* degi   = (int*)A3;
    int* cursor = degi + N;
    int* bsum   = cursor + N;

    const int NB = (N + 255) / 256;  // 782 <= 1024 (scan_top limit)

    // --- CSR build ---
    zero_ints<<<NB, 256, 0, stream>>>(degi, N);
    hist_kernel<<<(E + 255) / 256, 256, 0, stream>>>(dstp, degi, E);
    scan_reduce<<<NB, 256, 0, stream>>>(degi, bsum, N);
    scan_top<<<1, 1024, 0, stream>>>(bsum, NB);
    scan_final<<<NB, 256, 0, stream>>>(degi, bsum, rowptr, cursor, N, E);
    fill_kernel<<<(E + 255) / 256, 256, 0, stream>>>(src, dstp, cursor, csr, E);

    // --- layer 1: 128 -> 64 --- fp32 in, bf16 out; LDS-staged x (async DMA)
    // 48 KB LDS (16 W + 32 x-dbuf), 3 blocks/CU; grid 1536 = 768 node-blocks
    // x 2 ch classes, pairs (b, b^8) co-located per XCD.
    proj1_mfma<<<1536, 256, 0, stream>>>(x, Wl1, Wr1, bl1, A1, Bb, N);
    agg_bf16<64, 8><<<(int)(((long long)N * 8 + 255) / 256), 256, 0, stream>>>(
        rowptr, csr, A1, Bb, N);

    // --- layer 2: 64 -> 32 --- bf16 in (relu), bf16 out; CH=1, NU=2
    proj_mfma<64, 32, 32, 64, 1, 2, true, true, true><<<1563, 256, 0, stream>>>(
        Bb, Wl2, Wr2, bl2, A2, Cb, N);
    agg_bf16<32, 4><<<(int)(((long long)N * 4 + 255) / 256), 256, 0, stream>>>(
        rowptr, csr, A2, Cb, N);

    // --- layer 3: 32 -> 20 --- bf16 in (relu), fp32 out (p3=A3, r -> d_out)
    proj_mfma<32, 20, 20, 48, 1, 2, true, true, false><<<1563, 256, 0, stream>>>(
        Cb, Wl3, Wr3, bl3, A3, out, N);
    agg_f32<20, 8><<<(int)(((long long)N * 8 + 255) / 256), 256, 0, stream>>>(
        rowptr, csr, A3, out, N);
}

// Round 4
// 336.983 us; speedup vs baseline: 1.0871x; 1.0871x over previous
//
#include <hip/hip_runtime.h>
#include <hip/hip_bf16.h>

// ---------------------------------------------------------------------------
// GraphSAGE 3-layer encoder, fp32 in/out.
//   per layer: h_out = relu?( mean_agg(h)@Wl + b + h@Wr )
// Identity: segment_sum(h[src])@Wl == segment_sum((h@Wl)[src])
//   -> project first (MFMA bf16), aggregate small vectors via CSR gather.
// R10 -> R11:
//   * R10 post-mortem: traffic now IDEAL (FETCH 100->50.5 MB via XCD-paired
//     ch blocks; total ~103 MB) but SQ_LDS_BANK_CONFLICT=34.8M cycles =
//     ~67% of runtime. The [32][128] fp32 x tile is the documented G4 trap:
//     16 lanes read the same 16B column at 512B row stride -> 16-way.
//   * R11: XOR-swizzle via rule #21 (both-sides-or-neither with gload_lds):
//     LDS dest stays LINEAR (DMA), per-lane GLOBAL source column is
//     pre-swizzled (chunk c of row r -> slot c^(r&7)), and the ds_read
//     applies the same XOR. Read bank group becomes (q*2)^(ln&7): 8 distinct
//     across ln=0..7, 2-way for ln=8..15 (free per m136).
//   * Everything else unchanged (single-variable round).
// ---------------------------------------------------------------------------

typedef __attribute__((ext_vector_type(8))) short short8;
typedef __attribute__((ext_vector_type(4))) float f32x4;

__device__ inline unsigned short f2b(float x) {
    return __bfloat16_as_ushort(__float2bfloat16(x));
}
__device__ inline float b2f(unsigned short u) {
    return __uint_as_float(((unsigned)u) << 16);
}

__device__ __forceinline__ void gload_lds16(const void* g, void* l) {
    __builtin_amdgcn_global_load_lds(
        (const __attribute__((address_space(1))) void*)g,
        (__attribute__((address_space(3))) void*)l, 16, 0, 0);
}

// ============================ CSR construction =============================

__global__ void zero_ints(int* __restrict__ p, int n) {
    int i = blockIdx.x * blockDim.x + threadIdx.x;
    if (i < n) p[i] = 0;
}

__global__ void hist_kernel(const int* __restrict__ dst, int* __restrict__ deg, int E) {
    int i = blockIdx.x * blockDim.x + threadIdx.x;
    if (i < E) atomicAdd(&deg[dst[i]], 1);
}

__global__ void scan_reduce(const int* __restrict__ deg, int* __restrict__ bsum, int n) {
    __shared__ int s[256];
    int i = blockIdx.x * 256 + threadIdx.x;
    s[threadIdx.x] = (i < n) ? deg[i] : 0;
    __syncthreads();
    for (int off = 128; off > 0; off >>= 1) {
        if (threadIdx.x < off) s[threadIdx.x] += s[threadIdx.x + off];
        __syncthreads();
    }
    if (threadIdx.x == 0) bsum[blockIdx.x] = s[0];
}

__global__ void scan_top(int* __restrict__ bsum, int nb) {
    __shared__ int s[1024];
    int t = threadIdx.x;
    int v = (t < nb) ? bsum[t] : 0;
    s[t] = v;
    __syncthreads();
    for (int off = 1; off < 1024; off <<= 1) {
        int add = (t >= off) ? s[t - off] : 0;
        __syncthreads();
        s[t] += add;
        __syncthreads();
    }
    if (t < nb) bsum[t] = s[t] - v;  // exclusive
}

__global__ void scan_final(const int* __restrict__ deg, const int* __restrict__ bsum,
                           int* __restrict__ rowptr, int* __restrict__ cursor,
                           int n, int E) {
    __shared__ int s[256];
    int t = threadIdx.x;
    int i = blockIdx.x * 256 + t;
    int v = (i < n) ? deg[i] : 0;
    s[t] = v;
    __syncthreads();
    for (int off = 1; off < 256; off <<= 1) {
        int add = (t >= off) ? s[t - off] : 0;
        __syncthreads();
        s[t] += add;
        __syncthreads();
    }
    int excl = s[t] - v + bsum[blockIdx.x];
    if (i < n) {
        rowptr[i] = excl;
        cursor[i] = excl;
    }
    if (i == 0) rowptr[n] = E;
}

__global__ void fill_kernel(const int* __restrict__ src, const int* __restrict__ dst,
                            int* __restrict__ cursor, int* __restrict__ csr, int E) {
    int e = blockIdx.x * blockDim.x + threadIdx.x;
    if (e < E) {
        int pos = atomicAdd(&cursor[dst[e]], 1);
        csr[pos] = src[e];
    }
}

// ====================== layer-1 MFMA projection (LDS x) ====================
// 128 -> (64|64). p = x@Wl ; r = x@Wr + b. Weight cols concatenated
// [0,64)->p, [64,128)->r. CH=2 block col-split: ch = (b>>3)&1 so the two
// blocks of a pair (b, b^8) sit on the SAME XCD; each stages 16 KB of
// weight fragments (proven conflict-free fragment order, R6-R9).
// x: 32-row fp32 tiles, double-buffered in LDS via global_load_lds (16B),
// XOR-SWIZZLED: 16B chunk c of local row r lives at chunk slot c^(r&7).
// LDS dest linear (DMA constraint); swizzle applied on the per-lane GLOBAL
// source address and again on the ds_read side (rule #21 involution).
// Waves: 2 row-groups x 2 col-groups. A-fragments built per k-step from
// 2x ds_read_b128 + 8 cvt (transient regs only).
// MFMA 16x16x32: A[m=lane&15][k=(lane>>4)*8+i]; D col=lane&15,
// row=(lane>>4)*4+reg (verified R3-R6).

__launch_bounds__(256, 4)
__global__ void proj1_mfma(const float* __restrict__ x,
                           const float* __restrict__ Wl,
                           const float* __restrict__ Wr,
                           const float* __restrict__ bl,
                           unsigned short* __restrict__ pv,
                           unsigned short* __restrict__ rv,
                           int n) {
    constexpr int S = 4;             // k-steps (128/32)
    constexpr int TWB = 4;           // weight col-tiles staged per block
    constexpr int NCH = TWB * S * 64;

    __shared__ unsigned short sW[NCH * 8];   // 16 KB
    __shared__ float sX[2][32 * 128];        // 2 x 16 KB

    const int b = (int)blockIdx.x;
    const int ch = (b >> 3) & 1;
    const int blk = (b & 7) | ((b >> 4) << 3);
    const int nblk = (int)gridDim.x >> 1;

    const int tid = threadIdx.x;
    // stage this block's ch-half of weights as lane-ordered fragments
    for (int chunk = tid; chunk < NCH; chunk += 256) {
        const int lane_c = chunk & 63;
        const int rest = chunk >> 6;         // t*S + s
        const int s = rest % S;
        const int t = rest / S;
        const int c = (ch * TWB + t) * 16 + (lane_c & 15);
        const int k0 = s * 32 + (lane_c >> 4) * 8;
        short8 pack;
#pragma unroll
        for (int j = 0; j < 8; ++j) {
            const int k = k0 + j;
            float w = (c < 64) ? Wl[k * 64 + c] : Wr[k * 64 + (c - 64)];
            pack[j] = (short)f2b(w);
        }
        *reinterpret_cast<short8*>(&sW[(size_t)chunk * 8]) = pack;
    }

    const int wave = tid >> 6, lane = tid & 63;
    const int rg = wave & 1, cw = wave >> 1;   // row-group, col-group
    const int q = lane >> 4, ln = lane & 15;

    int colg[2];
    float bias[2];
#pragma unroll
    for (int t = 0; t < 2; ++t) {
        colg[t] = ch * 64 + (cw * 2 + t) * 16 + ln;
        bias[t] = (colg[t] >= 64) ? bl[colg[t] - 64] : 0.0f;
    }

    // async-stage one 32-row x tile into sX[d] (1024 x 16B chunks).
    // LDS slot ci holds global chunk (row = ci>>5, col = (ci&31) ^ (row&7)).
    auto stage = [&](int d, int nb) {
#pragma unroll
        for (int i = 0; i < 4; ++i) {
            const int cbase = wave * 256 + i * 64;       // wave-uniform
            const int ci = cbase + lane;
            const int rl = ci >> 5;                      // local row 0..31
            const int cc = ci & 31;                      // swizzled slot col
            int row = nb + rl;
            if (row >= n) row = n - 1;                   // clamp (stores guarded)
            const float* g = x + (size_t)row * 128 + (size_t)((cc ^ (rl & 7)) << 2);
            char* l = (char*)&sX[d][0] + (size_t)cbase * 16;
            gload_lds16(g, l);
        }
    };

    auto compute = [&](int d, int nb) {
        const int rowb = nb + rg * 16;
        const int rl = rg * 16 + ln;                     // local row
        const int swz = rl & 7;
        const float* xbase = &sX[d][(size_t)rl * 128];
        f32x4 acc0 = (f32x4){0.f, 0.f, 0.f, 0.f};
        f32x4 acc1 = (f32x4){0.f, 0.f, 0.f, 0.f};
        const int bt = cw * 2;
#pragma unroll
        for (int s = 0; s < S; ++s) {
            const int c0 = s * 8 + q * 2;                // 16B chunk col
            float4 v0 = *reinterpret_cast<const float4*>(xbase + ((c0 ^ swz) << 2));
            float4 v1 = *reinterpret_cast<const float4*>(xbase + (((c0 + 1) ^ swz) << 2));
            short8 a;
            a[0] = (short)f2b(v0.x); a[1] = (short)f2b(v0.y);
            a[2] = (short)f2b(v0.z); a[3] = (short)f2b(v0.w);
            a[4] = (short)f2b(v1.x); a[5] = (short)f2b(v1.y);
            a[6] = (short)f2b(v1.z); a[7] = (short)f2b(v1.w);
            short8 bf0 = *reinterpret_cast<const short8*>(
                &sW[((size_t)(bt * S + s)) * 512 + (size_t)lane * 8]);
            short8 bf1 = *reinterpret_cast<const short8*>(
                &sW[((size_t)((bt + 1) * S + s)) * 512 + (size_t)lane * 8]);
            acc0 = __builtin_amdgcn_mfma_f32_16x16x32_bf16(a, bf0, acc0, 0, 0, 0);
            acc1 = __builtin_amdgcn_mfma_f32_16x16x32_bf16(a, bf1, acc1, 0, 0, 0);
        }
#pragma unroll
        for (int t = 0; t < 2; ++t) {
            const f32x4 acc = t ? acc1 : acc0;
            const int c = colg[t];
#pragma unroll
            for (int rr = 0; rr < 4; ++rr) {
                const int row = rowb + q * 4 + rr;
                if (row < n) {
                    if (c < 64)
                        pv[(size_t)row * 64 + c] = f2b(acc[rr]);
                    else
                        rv[(size_t)row * 64 + (c - 64)] = f2b(acc[rr] + bias[t]);
                }
            }
        }
    };

    constexpr int npi = 32;
    const int stride = nblk * npi;
    int nb = blk * npi;
    if (nb >= n) return;
    stage(0, nb);
    __syncthreads();          // weights + tile0 ready
    while (true) {
        const int nb1 = nb + stride;
        if (nb1 < n) stage(1, nb1);
        compute(0, nb);
        __syncthreads();      // tile1 arrived; sX[0] free
        if (nb1 >= n) break;
        const int nb2 = nb1 + stride;
        if (nb2 < n) stage(0, nb2);
        compute(1, nb1);
        __syncthreads();
        nb = nb2;
        if (nb >= n) break;
    }
}

// ==================== layers 2/3 MFMA projection (regs) ====================
// bf16 input, small rows; R9 register path (VGPR<=64, works).

template <int DIN, int DP, int DR, int DT2, int CH, int NU,
          bool RELU, bool IN_BF16, bool OUT_BF16>
__launch_bounds__(256, 4)
__global__ void proj_mfma(const void* __restrict__ xv,
                          const float* __restrict__ Wl,
                          const float* __restrict__ Wr,
                          const float* __restrict__ bl,
                          void* __restrict__ pv,
                          void* __restrict__ rv,
                          int n) {
    constexpr int WAVES = 4;             // 256 threads
    constexpr int TILES = DT2 / 16;
    constexpr int TW = TILES / CH;       // col tiles per block (= per wave)
    constexpr int S = DIN / 32;          // MFMA k-steps
    constexpr int NCH = TW * S * 64;     // 16B fragment chunks staged/block

    __shared__ unsigned short sF[NCH * 8];

    const int ch   = (CH > 1) ? ((int)blockIdx.x % CH) : 0;
    const int blk  = (int)blockIdx.x / CH;
    const int nblk = (int)gridDim.x / CH;

    const int tid = threadIdx.x;
    // stage this block's ch-part of weights as lane-ordered fragments
    for (int chunk = tid; chunk < NCH; chunk += 256) {
        const int lane_c = chunk & 63;
        const int rest = chunk >> 6;         // t*S + s
        const int s = rest % S;
        const int t = rest / S;
        const int c = (ch * TW + t) * 16 + (lane_c & 15);
        const int k0 = s * 32 + (lane_c >> 4) * 8;
        short8 pack;
#pragma unroll
        for (int j = 0; j < 8; ++j) {
            float w = 0.f;
            const int k = k0 + j;
            if (c < DP) w = Wl[k * DP + c];
            else if (c < DP + DR) w = Wr[k * DR + (c - DP)];
            pack[j] = (short)f2b(w);
        }
        *reinterpret_cast<short8*>(&sF[(size_t)chunk * 8]) = pack;
    }
    __syncthreads();

    const int wave = tid >> 6, lane = tid & 63;
    const int ng = wave;                 // all waves in block share ch
    const int q = lane >> 4, ln = lane & 15;
    const int colbase = ch * (TW * 16);

    // lane's fragment base: frag (t,s) at +(t*S+s)*512 ushorts
    const unsigned short* fbase = &sF[(size_t)lane * 8];

    int colg[TW];
    float bias[TW];
#pragma unroll
    for (int t = 0; t < TW; ++t) {
        colg[t] = colbase + t * 16 + ln;
        bias[t] = (colg[t] >= DP && colg[t] < DP + DR) ? bl[colg[t] - DP] : 0.0f;
    }

    // raw-x double buffers (unused dtype pair is DCE'd)
    float4 rf0[NU][2 * S], rf1[NU][2 * S];
    short8 rb0[NU][S], rb1[NU][S];

    auto load_groups = [&](float4 (&rf)[NU][2 * S], short8 (&rb)[NU][S], int nbase) {
#pragma unroll
        for (int g = 0; g < NU; ++g) {
            const int base = nbase + (ng * NU + g) * 16;
            if (base >= n) continue;  // wave-uniform
            if constexpr (IN_BF16) {
                const unsigned short* xr =
                    (const unsigned short*)xv + (size_t)(base + ln) * DIN + q * 8;
#pragma unroll
                for (int s = 0; s < S; ++s)
                    rb[g][s] = *reinterpret_cast<const short8*>(xr + s * 32);
            } else {
                const float* xr = (const float*)xv + (size_t)(base + ln) * DIN + q * 8;
#pragma unroll
                for (int s = 0; s < S; ++s) {
                    rf[g][2 * s]     = *reinterpret_cast<const float4*>(xr + s * 32);
                    rf[g][2 * s + 1] = *reinterpret_cast<const float4*>(xr + s * 32 + 4);
                }
            }
        }
    };

    auto compute_groups = [&](float4 (&rf)[NU][2 * S], short8 (&rb)[NU][S], int nbase) {
#pragma unroll
        for (int g = 0; g < NU; ++g) {
            const int base = nbase + (ng * NU + g) * 16;
            if (base >= n) continue;
            short8 af[S];
#pragma unroll
            for (int s = 0; s < S; ++s) {
                if constexpr (IN_BF16) {
                    short8 a = rb[g][s];
                    if (RELU) {
#pragma unroll
                        for (int j = 0; j < 8; ++j)
                            a[j] = ((short)a[j] < 0) ? (short)0 : a[j];
                    }
                    af[s] = a;
                } else {
                    float4 v0 = rf[g][2 * s], v1 = rf[g][2 * s + 1];
                    if (RELU) {
                        v0.x = fmaxf(v0.x, 0.0f); v0.y = fmaxf(v0.y, 0.0f);
                        v0.z = fmaxf(v0.z, 0.0f); v0.w = fmaxf(v0.w, 0.0f);
                        v1.x = fmaxf(v1.x, 0.0f); v1.y = fmaxf(v1.y, 0.0f);
                        v1.z = fmaxf(v1.z, 0.0f); v1.w = fmaxf(v1.w, 0.0f);
                    }
                    short8 a;
                    a[0] = (short)f2b(v0.x); a[1] = (short)f2b(v0.y);
                    a[2] = (short)f2b(v0.z); a[3] = (short)f2b(v0.w);
                    a[4] = (short)f2b(v1.x); a[5] = (short)f2b(v1.y);
                    a[6] = (short)f2b(v1.z); a[7] = (short)f2b(v1.w);
                    af[s] = a;
                }
            }

            f32x4 acc[TW];
#pragma unroll
            for (int t = 0; t < TW; ++t) acc[t] = (f32x4){0.f, 0.f, 0.f, 0.f};
#pragma unroll
            for (int s = 0; s < S; ++s)
#pragma unroll
                for (int t = 0; t < TW; ++t) {
                    short8 bf = *reinterpret_cast<const short8*>(
                        fbase + (size_t)(t * S + s) * 512);
                    acc[t] = __builtin_amdgcn_mfma_f32_16x16x32_bf16(
                        af[s], bf, acc[t], 0, 0, 0);
                }

#pragma unroll
            for (int t = 0; t < TW; ++t) {
                const int c = colg[t];
#pragma unroll
                for (int rr = 0; rr < 4; ++rr) {
                    const int row = base + q * 4 + rr;
                    if (c < DP) {
                        if constexpr (OUT_BF16)
                            ((unsigned short*)pv)[(size_t)row * DP + c] = f2b(acc[t][rr]);
                        else
                            ((float*)pv)[(size_t)row * DP + c] = acc[t][rr];
                    } else if (c < DP + DR) {
                        const float v = acc[t][rr] + bias[t];
                        if constexpr (OUT_BF16)
                            ((unsigned short*)rv)[(size_t)row * DR + (c - DP)] = f2b(v);
                        else
                            ((float*)rv)[(size_t)row * DR + (c - DP)] = v;
                    }
                }
            }
        }
    };

    const int npi = WAVES * NU * 16;     // nodes per block-iteration
    const int stride = nblk * npi;
    int nb = blk * npi;
    if (nb >= n) return;
    load_groups(rf0, rb0, nb);
    while (true) {
        const int nb1 = nb + stride;
        if (nb1 < n) load_groups(rf1, rb1, nb1);
        compute_groups(rf0, rb0, nb);
        nb = nb1;
        if (nb >= n) break;
        const int nb2 = nb + stride;
        if (nb2 < n) load_groups(rf0, rb0, nb2);
        compute_groups(rf1, rb1, nb);
        nb = nb2;
        if (nb >= n) break;
    }
}

// ============================ aggregation ==================================
// out[d] += mean over csr row of p rows. bf16 buffers: L=D/8 lanes per node,
// one short8 per lane per gathered row; fp32 accumulation; unroll-4 keeps
// 4 independent csr->row chains in flight.

template <int D, int L>
__global__ void agg_bf16(const int* __restrict__ rowptr,
                         const int* __restrict__ csr,
                         const unsigned short* __restrict__ p,
                         unsigned short* __restrict__ out,
                         int n) {
    constexpr int RQ = D / 8;            // short8s per row
    long long gid = (long long)blockIdx.x * blockDim.x + threadIdx.x;
    int d = (int)(gid / L);
    int l = (int)(gid % L);
    if (d >= n) return;
    int beg = rowptr[d], end = rowptr[d + 1];
    int deg = end - beg;
    if (deg <= 0) return;

    const short8* pr = reinterpret_cast<const short8*>(p);
    float s[8];
#pragma unroll
    for (int j = 0; j < 8; ++j) s[j] = 0.0f;

    int i = beg;
    for (; i + 4 <= end; i += 4) {
        int e0 = csr[i], e1 = csr[i + 1], e2 = csr[i + 2], e3 = csr[i + 3];
        short8 a = pr[(size_t)e0 * RQ + l];
        short8 b = pr[(size_t)e1 * RQ + l];
        short8 c = pr[(size_t)e2 * RQ + l];
        short8 e = pr[(size_t)e3 * RQ + l];
#pragma unroll
        for (int j = 0; j < 8; ++j)
            s[j] += (b2f((unsigned short)a[j]) + b2f((unsigned short)b[j])) +
                    (b2f((unsigned short)c[j]) + b2f((unsigned short)e[j]));
    }
    for (; i < end; ++i) {
        short8 a = pr[(size_t)csr[i] * RQ + l];
#pragma unroll
        for (int j = 0; j < 8; ++j) s[j] += b2f((unsigned short)a[j]);
    }

    const float inv = 1.0f / (float)deg;
    short8* o = reinterpret_cast<short8*>(out) + (size_t)d * RQ + l;
    short8 cur = *o;
#pragma unroll
    for (int j = 0; j < 8; ++j) {
        float v = b2f((unsigned short)cur[j]) + s[j] * inv;
        cur[j] = (short)f2b(v);
    }
    *o = cur;
}

// fp32 variant for the final layer (out = d_out, fp32)
template <int D, int L>
__global__ void agg_f32(const int* __restrict__ rowptr,
                        const int* __restrict__ csr,
                        const float* __restrict__ p,
                        float* __restrict__ out,
                        int n) {
    constexpr int RQ = D / 4;            // float4s per row
    long long gid = (long long)blockIdx.x * blockDim.x + threadIdx.x;
    int d = (int)(gid / L);
    int l = (int)(gid % L);
    if (d >= n || l >= RQ) return;
    int beg = rowptr[d], end = rowptr[d + 1];
    int deg = end - beg;
    if (deg <= 0) return;

    const float4* pr = reinterpret_cast<const float4*>(p);
    float sx = 0.f, sy = 0.f, sz = 0.f, sw = 0.f;
    int i = beg;
    for (; i + 4 <= end; i += 4) {
        int s0 = csr[i], s1 = csr[i + 1], s2 = csr[i + 2], s3 = csr[i + 3];
        float4 a = pr[(size_t)s0 * RQ + l];
        float4 b = pr[(size_t)s1 * RQ + l];
        float4 c = pr[(size_t)s2 * RQ + l];
        float4 e = pr[(size_t)s3 * RQ + l];
        sx += (a.x + b.x) + (c.x + e.x);
        sy += (a.y + b.y) + (c.y + e.y);
        sz += (a.z + b.z) + (c.z + e.z);
        sw += (a.w + b.w) + (c.w + e.w);
    }
    for (; i < end; ++i) {
        float4 a = pr[(size_t)csr[i] * RQ + l];
        sx += a.x; sy += a.y; sz += a.z; sw += a.w;
    }
    const float inv = 1.0f / (float)deg;
    float4* o = reinterpret_cast<float4*>(out) + (size_t)d * RQ + l;
    float4 cur = *o;
    cur.x += sx * inv; cur.y += sy * inv;
    cur.z += sz * inv; cur.w += sw * inv;
    *o = cur;
}

// ============================ launcher =====================================

extern "C" void kernel_launch(void* const* d_in, const int* in_sizes, int n_in,
                              void* d_out, int out_size, void* d_ws, size_t ws_size,
                              hipStream_t stream) {
    const float* x   = (const float*)d_in[0];
    const int*   ei  = (const int*)d_in[1];   // (2, E) int32
    const float* Wl1 = (const float*)d_in[2];
    const float* bl1 = (const float*)d_in[3];
    const float* Wr1 = (const float*)d_in[4];
    const float* Wl2 = (const float*)d_in[5];
    const float* bl2 = (const float*)d_in[6];
    const float* Wr2 = (const float*)d_in[7];
    const float* Wl3 = (const float*)d_in[8];
    const float* bl3 = (const float*)d_in[9];
    const float* Wr3 = (const float*)d_in[10];
    float* out = (float*)d_out;

    const int N = in_sizes[0] / 128;
    const int E = in_sizes[1] / 2;
    const int* src  = ei;
    const int* dstp = ei + E;

    // workspace (bf16 intermediates):
    //   A1 bf16 N*64 | B bf16 N*64 | A2 bf16 N*32 | C bf16 N*32 |
    //   A3 f32 N*20 | rowptr (N+1) | csr (E)
    // transient CSR ints (degi, cursor, bsum) alias A3 (dead before proj3).
    unsigned short* A1 = (unsigned short*)d_ws;
    unsigned short* Bb = A1 + (size_t)N * 64;
    unsigned short* A2 = Bb + (size_t)N * 64;
    unsigned short* Cb = A2 + (size_t)N * 32;
    float* A3 = (float*)(Cb + (size_t)N * 32);
    int* rowptr = (int*)(A3 + (size_t)N * 20);
    int* csr    = rowptr + (N + 1);

    int* degi   = (int*)A3;
    int* cursor = degi + N;
    int* bsum   = cursor + N;

    const int NB = (N + 255) / 256;  // 782 <= 1024 (scan_top limit)

    // --- CSR build ---
    zero_ints<<<NB, 256, 0, stream>>>(degi, N);
    hist_kernel<<<(E + 255) / 256, 256, 0, stream>>>(dstp, degi, E);
    scan_reduce<<<NB, 256, 0, stream>>>(degi, bsum, N);
    scan_top<<<1, 1024, 0, stream>>>(bsum, NB);
    scan_final<<<NB, 256, 0, stream>>>(degi, bsum, rowptr, cursor, N, E);
    fill_kernel<<<(E + 255) / 256, 256, 0, stream>>>(src, dstp, cursor, csr, E);

    // --- layer 1: 128 -> 64 --- fp32 in, bf16 out; LDS-staged x (async DMA)
    // 48 KB LDS (16 W + 32 x-dbuf swizzled), 3 blocks/CU; grid 1536 =
    // 768 node-blocks x 2 ch classes, pairs (b, b^8) co-located per XCD.
    proj1_mfma<<<1536, 256, 0, stream>>>(x, Wl1, Wr1, bl1, A1, Bb, N);
    agg_bf16<64, 8><<<(int)(((long long)N * 8 + 255) / 256), 256, 0, stream>>>(
        rowptr, csr, A1, Bb, N);

    // --- layer 2: 64 -> 32 --- bf16 in (relu), bf16 out; CH=1, NU=2
    proj_mfma<64, 32, 32, 64, 1, 2, true, true, true><<<1563, 256, 0, stream>>>(
        Bb, Wl2, Wr2, bl2, A2, Cb, N);
    agg_bf16<32, 4><<<(int)(((long long)N * 4 + 255) / 256), 256, 0, stream>>>(
        rowptr, csr, A2, Cb, N);

    // --- layer 3: 32 -> 20 --- bf16 in (relu), fp32 out (p3=A3, r -> d_out)
    proj_mfma<32, 20, 20, 48, 1, 2, true, true, false><<<1563, 256, 0, stream>>>(
        Cb, Wl3, Wr3, bl3, A3, out, N);
    agg_f32<20, 8><<<(int)(((long long)N * 8 + 255) / 256), 256, 0, stream>>>(
        rowptr, csr, A3, out, N);
}

// Round 5
// 335.743 us; speedup vs baseline: 1.0911x; 1.0037x over previous
//
#include <hip/hip_runtime.h>
#include <hip/hip_bf16.h>

// ---------------------------------------------------------------------------
// GraphSAGE 3-layer encoder, fp32 in/out.
//   per layer: h_out = relu?( mean_agg(h)@Wl + b + h@Wr )
// Identity: segment_sum(h[src])@Wl == segment_sum((h@Wl)[src])
//   -> project first (MFMA bf16), aggregate small vectors via CSR gather.
// R11 -> R12:
//   * R11 post-mortem: swizzle worked (total -29 us, proj1 ~55 us inferred;
//     proj1 now below the harness's 59-us workspace-poison fills, so the
//     profile top-5 is blind). proj1 still ~2x its ~25 us traffic floor.
//   * Duty-cycle theory: __syncthreads drains vmcnt(0) every tile, capping
//     DMA depth at 1 tile/block; 16 KB tiles -> high barrier rate, DMA pipe
//     idles. R12: 64-row tiles (32 KB), dbuf 64 KB + 16 KB W = 80 KB LDS ->
//     2 staggered blocks/CU, 4x compute per barrier (TW=4/wave, 16 MFMA).
//     launch_bounds(256,2) gives VGPR headroom (no R8-style spill).
//   * agg3: L=5 (was 8 with 3 dead lanes/node) -> 37% fewer waves.
//   * Everything else unchanged.
// ---------------------------------------------------------------------------

typedef __attribute__((ext_vector_type(8))) short short8;
typedef __attribute__((ext_vector_type(4))) float f32x4;

__device__ inline unsigned short f2b(float x) {
    return __bfloat16_as_ushort(__float2bfloat16(x));
}
__device__ inline float b2f(unsigned short u) {
    return __uint_as_float(((unsigned)u) << 16);
}

__device__ __forceinline__ void gload_lds16(const void* g, void* l) {
    __builtin_amdgcn_global_load_lds(
        (const __attribute__((address_space(1))) void*)g,
        (__attribute__((address_space(3))) void*)l, 16, 0, 0);
}

// ============================ CSR construction =============================

__global__ void zero_ints(int* __restrict__ p, int n) {
    int i = blockIdx.x * blockDim.x + threadIdx.x;
    if (i < n) p[i] = 0;
}

__global__ void hist_kernel(const int* __restrict__ dst, int* __restrict__ deg, int E) {
    int i = blockIdx.x * blockDim.x + threadIdx.x;
    if (i < E) atomicAdd(&deg[dst[i]], 1);
}

__global__ void scan_reduce(const int* __restrict__ deg, int* __restrict__ bsum, int n) {
    __shared__ int s[256];
    int i = blockIdx.x * 256 + threadIdx.x;
    s[threadIdx.x] = (i < n) ? deg[i] : 0;
    __syncthreads();
    for (int off = 128; off > 0; off >>= 1) {
        if (threadIdx.x < off) s[threadIdx.x] += s[threadIdx.x + off];
        __syncthreads();
    }
    if (threadIdx.x == 0) bsum[blockIdx.x] = s[0];
}

__global__ void scan_top(int* __restrict__ bsum, int nb) {
    __shared__ int s[1024];
    int t = threadIdx.x;
    int v = (t < nb) ? bsum[t] : 0;
    s[t] = v;
    __syncthreads();
    for (int off = 1; off < 1024; off <<= 1) {
        int add = (t >= off) ? s[t - off] : 0;
        __syncthreads();
        s[t] += add;
        __syncthreads();
    }
    if (t < nb) bsum[t] = s[t] - v;  // exclusive
}

__global__ void scan_final(const int* __restrict__ deg, const int* __restrict__ bsum,
                           int* __restrict__ rowptr, int* __restrict__ cursor,
                           int n, int E) {
    __shared__ int s[256];
    int t = threadIdx.x;
    int i = blockIdx.x * 256 + t;
    int v = (i < n) ? deg[i] : 0;
    s[t] = v;
    __syncthreads();
    for (int off = 1; off < 256; off <<= 1) {
        int add = (t >= off) ? s[t - off] : 0;
        __syncthreads();
        s[t] += add;
        __syncthreads();
    }
    int excl = s[t] - v + bsum[blockIdx.x];
    if (i < n) {
        rowptr[i] = excl;
        cursor[i] = excl;
    }
    if (i == 0) rowptr[n] = E;
}

__global__ void fill_kernel(const int* __restrict__ src, const int* __restrict__ dst,
                            int* __restrict__ cursor, int* __restrict__ csr, int E) {
    int e = blockIdx.x * blockDim.x + threadIdx.x;
    if (e < E) {
        int pos = atomicAdd(&cursor[dst[e]], 1);
        csr[pos] = src[e];
    }
}

// ====================== layer-1 MFMA projection (LDS x) ====================
// 128 -> (64|64). p = x@Wl ; r = x@Wr + b. Weight cols concatenated
// [0,64)->p, [64,128)->r. CH=2 block col-split: ch = (b>>3)&1 so the two
// blocks of a pair (b, b^8) sit on the SAME XCD; each stages 16 KB of
// weight fragments (proven conflict-free fragment order, R6-R11).
// x: 64-row fp32 tiles, double-buffered in LDS via global_load_lds (16B),
// XOR-SWIZZLED (R11): 16B chunk c of local row r lives at slot c^(r&7);
// swizzle applied on the per-lane GLOBAL source and again on ds_read.
// Waves = 4 row-groups of 16; each wave covers all 4 col-tiles of the
// block's ch-half (TW=4, 16 MFMA per tile per wave).
// MFMA 16x16x32: A[m=lane&15][k=(lane>>4)*8+i]; D col=lane&15,
// row=(lane>>4)*4+reg (verified R3-R6).

__launch_bounds__(256, 2)
__global__ void proj1_mfma(const float* __restrict__ x,
                           const float* __restrict__ Wl,
                           const float* __restrict__ Wr,
                           const float* __restrict__ bl,
                           unsigned short* __restrict__ pv,
                           unsigned short* __restrict__ rv,
                           int n) {
    constexpr int S = 4;             // k-steps (128/32)
    constexpr int TWB = 4;           // weight col-tiles staged per block
    constexpr int NCH = TWB * S * 64;

    __shared__ unsigned short sW[NCH * 8];   // 16 KB
    __shared__ float sX[2][64 * 128];        // 2 x 32 KB

    const int b = (int)blockIdx.x;
    const int ch = (b >> 3) & 1;
    const int blk = (b & 7) | ((b >> 4) << 3);
    const int nblk = (int)gridDim.x >> 1;

    const int tid = threadIdx.x;
    // stage this block's ch-half of weights as lane-ordered fragments
    for (int chunk = tid; chunk < NCH; chunk += 256) {
        const int lane_c = chunk & 63;
        const int rest = chunk >> 6;         // t*S + s
        const int s = rest % S;
        const int t = rest / S;
        const int c = (ch * TWB + t) * 16 + (lane_c & 15);
        const int k0 = s * 32 + (lane_c >> 4) * 8;
        short8 pack;
#pragma unroll
        for (int j = 0; j < 8; ++j) {
            const int k = k0 + j;
            float w = (c < 64) ? Wl[k * 64 + c] : Wr[k * 64 + (c - 64)];
            pack[j] = (short)f2b(w);
        }
        *reinterpret_cast<short8*>(&sW[(size_t)chunk * 8]) = pack;
    }

    const int wave = tid >> 6, lane = tid & 63;
    const int rg = wave;                     // row-group 0..3
    const int q = lane >> 4, ln = lane & 15;

    int colg[4];
    float bias[4];
#pragma unroll
    for (int t = 0; t < 4; ++t) {
        colg[t] = ch * 64 + t * 16 + ln;
        bias[t] = (colg[t] >= 64) ? bl[colg[t] - 64] : 0.0f;
    }

    // async-stage one 64-row x tile into sX[d] (2048 x 16B chunks).
    // LDS slot ci holds global chunk (row = ci>>5, col = (ci&31) ^ (row&7)).
    auto stage = [&](int d, int nb) {
#pragma unroll
        for (int i = 0; i < 8; ++i) {
            const int cbase = wave * 512 + i * 64;       // wave-uniform
            const int ci = cbase + lane;
            const int rl = ci >> 5;                      // local row 0..63
            const int cc = ci & 31;                      // swizzled slot col
            int row = nb + rl;
            if (row >= n) row = n - 1;                   // clamp (stores guarded)
            const float* g = x + (size_t)row * 128 + (size_t)((cc ^ (rl & 7)) << 2);
            char* l = (char*)&sX[d][0] + (size_t)cbase * 16;
            gload_lds16(g, l);
        }
    };

    auto compute = [&](int d, int nb) {
        const int rowb = nb + rg * 16;
        const int rl = rg * 16 + ln;                     // local row
        const int swz = rl & 7;
        const float* xbase = &sX[d][(size_t)rl * 128];
        f32x4 acc[4];
#pragma unroll
        for (int t = 0; t < 4; ++t) acc[t] = (f32x4){0.f, 0.f, 0.f, 0.f};
#pragma unroll
        for (int s = 0; s < S; ++s) {
            const int c0 = s * 8 + q * 2;                // 16B chunk col
            float4 v0 = *reinterpret_cast<const float4*>(xbase + ((c0 ^ swz) << 2));
            float4 v1 = *reinterpret_cast<const float4*>(xbase + (((c0 + 1) ^ swz) << 2));
            short8 a;
            a[0] = (short)f2b(v0.x); a[1] = (short)f2b(v0.y);
            a[2] = (short)f2b(v0.z); a[3] = (short)f2b(v0.w);
            a[4] = (short)f2b(v1.x); a[5] = (short)f2b(v1.y);
            a[6] = (short)f2b(v1.z); a[7] = (short)f2b(v1.w);
#pragma unroll
            for (int t = 0; t < 4; ++t) {
                short8 bf = *reinterpret_cast<const short8*>(
                    &sW[((size_t)(t * S + s)) * 512 + (size_t)lane * 8]);
                acc[t] = __builtin_amdgcn_mfma_f32_16x16x32_bf16(a, bf, acc[t], 0, 0, 0);
            }
        }
#pragma unroll
        for (int t = 0; t < 4; ++t) {
            const int c = colg[t];
#pragma unroll
            for (int rr = 0; rr < 4; ++rr) {
                const int row = rowb + q * 4 + rr;
                if (row < n) {
                    if (c < 64)
                        pv[(size_t)row * 64 + c] = f2b(acc[t][rr]);
                    else
                        rv[(size_t)row * 64 + (c - 64)] = f2b(acc[t][rr] + bias[t]);
                }
            }
        }
    };

    constexpr int npi = 64;
    const int stride = nblk * npi;
    int nb = blk * npi;
    if (nb >= n) return;
    stage(0, nb);
    __syncthreads();          // weights + tile0 ready
    while (true) {
        const int nb1 = nb + stride;
        if (nb1 < n) stage(1, nb1);
        compute(0, nb);
        __syncthreads();      // tile1 arrived; sX[0] free
        if (nb1 >= n) break;
        const int nb2 = nb1 + stride;
        if (nb2 < n) stage(0, nb2);
        compute(1, nb1);
        __syncthreads();
        nb = nb2;
        if (nb >= n) break;
    }
}

// ==================== layers 2/3 MFMA projection (regs) ====================
// bf16 input, small rows; R9 register path (VGPR<=64, works).

template <int DIN, int DP, int DR, int DT2, int CH, int NU,
          bool RELU, bool IN_BF16, bool OUT_BF16>
__launch_bounds__(256, 4)
__global__ void proj_mfma(const void* __restrict__ xv,
                          const float* __restrict__ Wl,
                          const float* __restrict__ Wr,
                          const float* __restrict__ bl,
                          void* __restrict__ pv,
                          void* __restrict__ rv,
                          int n) {
    constexpr int WAVES = 4;             // 256 threads
    constexpr int TILES = DT2 / 16;
    constexpr int TW = TILES / CH;       // col tiles per block (= per wave)
    constexpr int S = DIN / 32;          // MFMA k-steps
    constexpr int NCH = TW * S * 64;     // 16B fragment chunks staged/block

    __shared__ unsigned short sF[NCH * 8];

    const int ch   = (CH > 1) ? ((int)blockIdx.x % CH) : 0;
    const int blk  = (int)blockIdx.x / CH;
    const int nblk = (int)gridDim.x / CH;

    const int tid = threadIdx.x;
    // stage this block's ch-part of weights as lane-ordered fragments
    for (int chunk = tid; chunk < NCH; chunk += 256) {
        const int lane_c = chunk & 63;
        const int rest = chunk >> 6;         // t*S + s
        const int s = rest % S;
        const int t = rest / S;
        const int c = (ch * TW + t) * 16 + (lane_c & 15);
        const int k0 = s * 32 + (lane_c >> 4) * 8;
        short8 pack;
#pragma unroll
        for (int j = 0; j < 8; ++j) {
            float w = 0.f;
            const int k = k0 + j;
            if (c < DP) w = Wl[k * DP + c];
            else if (c < DP + DR) w = Wr[k * DR + (c - DP)];
            pack[j] = (short)f2b(w);
        }
        *reinterpret_cast<short8*>(&sF[(size_t)chunk * 8]) = pack;
    }
    __syncthreads();

    const int wave = tid >> 6, lane = tid & 63;
    const int ng = wave;                 // all waves in block share ch
    const int q = lane >> 4, ln = lane & 15;
    const int colbase = ch * (TW * 16);

    // lane's fragment base: frag (t,s) at +(t*S+s)*512 ushorts
    const unsigned short* fbase = &sF[(size_t)lane * 8];

    int colg[TW];
    float bias[TW];
#pragma unroll
    for (int t = 0; t < TW; ++t) {
        colg[t] = colbase + t * 16 + ln;
        bias[t] = (colg[t] >= DP && colg[t] < DP + DR) ? bl[colg[t] - DP] : 0.0f;
    }

    // raw-x double buffers (unused dtype pair is DCE'd)
    float4 rf0[NU][2 * S], rf1[NU][2 * S];
    short8 rb0[NU][S], rb1[NU][S];

    auto load_groups = [&](float4 (&rf)[NU][2 * S], short8 (&rb)[NU][S], int nbase) {
#pragma unroll
        for (int g = 0; g < NU; ++g) {
            const int base = nbase + (ng * NU + g) * 16;
            if (base >= n) continue;  // wave-uniform
            if constexpr (IN_BF16) {
                const unsigned short* xr =
                    (const unsigned short*)xv + (size_t)(base + ln) * DIN + q * 8;
#pragma unroll
                for (int s = 0; s < S; ++s)
                    rb[g][s] = *reinterpret_cast<const short8*>(xr + s * 32);
            } else {
                const float* xr = (const float*)xv + (size_t)(base + ln) * DIN + q * 8;
#pragma unroll
                for (int s = 0; s < S; ++s) {
                    rf[g][2 * s]     = *reinterpret_cast<const float4*>(xr + s * 32);
                    rf[g][2 * s + 1] = *reinterpret_cast<const float4*>(xr + s * 32 + 4);
                }
            }
        }
    };

    auto compute_groups = [&](float4 (&rf)[NU][2 * S], short8 (&rb)[NU][S], int nbase) {
#pragma unroll
        for (int g = 0; g < NU; ++g) {
            const int base = nbase + (ng * NU + g) * 16;
            if (base >= n) continue;
            short8 af[S];
#pragma unroll
            for (int s = 0; s < S; ++s) {
                if constexpr (IN_BF16) {
                    short8 a = rb[g][s];
                    if (RELU) {
#pragma unroll
                        for (int j = 0; j < 8; ++j)
                            a[j] = ((short)a[j] < 0) ? (short)0 : a[j];
                    }
                    af[s] = a;
                } else {
                    float4 v0 = rf[g][2 * s], v1 = rf[g][2 * s + 1];
                    if (RELU) {
                        v0.x = fmaxf(v0.x, 0.0f); v0.y = fmaxf(v0.y, 0.0f);
                        v0.z = fmaxf(v0.z, 0.0f); v0.w = fmaxf(v0.w, 0.0f);
                        v1.x = fmaxf(v1.x, 0.0f); v1.y = fmaxf(v1.y, 0.0f);
                        v1.z = fmaxf(v1.z, 0.0f); v1.w = fmaxf(v1.w, 0.0f);
                    }
                    short8 a;
                    a[0] = (short)f2b(v0.x); a[1] = (short)f2b(v0.y);
                    a[2] = (short)f2b(v0.z); a[3] = (short)f2b(v0.w);
                    a[4] = (short)f2b(v1.x); a[5] = (short)f2b(v1.y);
                    a[6] = (short)f2b(v1.z); a[7] = (short)f2b(v1.w);
                    af[s] = a;
                }
            }

            f32x4 acc[TW];
#pragma unroll
            for (int t = 0; t < TW; ++t) acc[t] = (f32x4){0.f, 0.f, 0.f, 0.f};
#pragma unroll
            for (int s = 0; s < S; ++s)
#pragma unroll
                for (int t = 0; t < TW; ++t) {
                    short8 bf = *reinterpret_cast<const short8*>(
                        fbase + (size_t)(t * S + s) * 512);
                    acc[t] = __builtin_amdgcn_mfma_f32_16x16x32_bf16(
                        af[s], bf, acc[t], 0, 0, 0);
                }

#pragma unroll
            for (int t = 0; t < TW; ++t) {
                const int c = colg[t];
#pragma unroll
                for (int rr = 0; rr < 4; ++rr) {
                    const int row = base + q * 4 + rr;
                    if (c < DP) {
                        if constexpr (OUT_BF16)
                            ((unsigned short*)pv)[(size_t)row * DP + c] = f2b(acc[t][rr]);
                        else
                            ((float*)pv)[(size_t)row * DP + c] = acc[t][rr];
                    } else if (c < DP + DR) {
                        const float v = acc[t][rr] + bias[t];
                        if constexpr (OUT_BF16)
                            ((unsigned short*)rv)[(size_t)row * DR + (c - DP)] = f2b(v);
                        else
                            ((float*)rv)[(size_t)row * DR + (c - DP)] = v;
                    }
                }
            }
        }
    };

    const int npi = WAVES * NU * 16;     // nodes per block-iteration
    const int stride = nblk * npi;
    int nb = blk * npi;
    if (nb >= n) return;
    load_groups(rf0, rb0, nb);
    while (true) {
        const int nb1 = nb + stride;
        if (nb1 < n) load_groups(rf1, rb1, nb1);
        compute_groups(rf0, rb0, nb);
        nb = nb1;
        if (nb >= n) break;
        const int nb2 = nb + stride;
        if (nb2 < n) load_groups(rf0, rb0, nb2);
        compute_groups(rf1, rb1, nb);
        nb = nb2;
        if (nb >= n) break;
    }
}

// ============================ aggregation ==================================
// out[d] += mean over csr row of p rows. bf16 buffers: L=D/8 lanes per node,
// one short8 per lane per gathered row; fp32 accumulation; unroll-4 keeps
// 4 independent csr->row chains in flight.

template <int D, int L>
__global__ void agg_bf16(const int* __restrict__ rowptr,
                         const int* __restrict__ csr,
                         const unsigned short* __restrict__ p,
                         unsigned short* __restrict__ out,
                         int n) {
    constexpr int RQ = D / 8;            // short8s per row
    long long gid = (long long)blockIdx.x * blockDim.x + threadIdx.x;
    int d = (int)(gid / L);
    int l = (int)(gid % L);
    if (d >= n) return;
    int beg = rowptr[d], end = rowptr[d + 1];
    int deg = end - beg;
    if (deg <= 0) return;

    const short8* pr = reinterpret_cast<const short8*>(p);
    float s[8];
#pragma unroll
    for (int j = 0; j < 8; ++j) s[j] = 0.0f;

    int i = beg;
    for (; i + 4 <= end; i += 4) {
        int e0 = csr[i], e1 = csr[i + 1], e2 = csr[i + 2], e3 = csr[i + 3];
        short8 a = pr[(size_t)e0 * RQ + l];
        short8 b = pr[(size_t)e1 * RQ + l];
        short8 c = pr[(size_t)e2 * RQ + l];
        short8 e = pr[(size_t)e3 * RQ + l];
#pragma unroll
        for (int j = 0; j < 8; ++j)
            s[j] += (b2f((unsigned short)a[j]) + b2f((unsigned short)b[j])) +
                    (b2f((unsigned short)c[j]) + b2f((unsigned short)e[j]));
    }
    for (; i < end; ++i) {
        short8 a = pr[(size_t)csr[i] * RQ + l];
#pragma unroll
        for (int j = 0; j < 8; ++j) s[j] += b2f((unsigned short)a[j]);
    }

    const float inv = 1.0f / (float)deg;
    short8* o = reinterpret_cast<short8*>(out) + (size_t)d * RQ + l;
    short8 cur = *o;
#pragma unroll
    for (int j = 0; j < 8; ++j) {
        float v = b2f((unsigned short)cur[j]) + s[j] * inv;
        cur[j] = (short)f2b(v);
    }
    *o = cur;
}

// fp32 variant for the final layer (out = d_out, fp32); L lanes per node,
// one float4 per lane (L == D/4, all lanes active).
template <int D, int L>
__global__ void agg_f32(const int* __restrict__ rowptr,
                        const int* __restrict__ csr,
                        const float* __restrict__ p,
                        float* __restrict__ out,
                        int n) {
    constexpr int RQ = D / 4;            // float4s per row
    static_assert(L == RQ, "agg_f32: one float4 per lane");
    long long gid = (long long)blockIdx.x * blockDim.x + threadIdx.x;
    int d = (int)(gid / L);
    int l = (int)(gid % L);
    if (d >= n) return;
    int beg = rowptr[d], end = rowptr[d + 1];
    int deg = end - beg;
    if (deg <= 0) return;

    const float4* pr = reinterpret_cast<const float4*>(p);
    float sx = 0.f, sy = 0.f, sz = 0.f, sw = 0.f;
    int i = beg;
    for (; i + 4 <= end; i += 4) {
        int s0 = csr[i], s1 = csr[i + 1], s2 = csr[i + 2], s3 = csr[i + 3];
        float4 a = pr[(size_t)s0 * RQ + l];
        float4 b = pr[(size_t)s1 * RQ + l];
        float4 c = pr[(size_t)s2 * RQ + l];
        float4 e = pr[(size_t)s3 * RQ + l];
        sx += (a.x + b.x) + (c.x + e.x);
        sy += (a.y + b.y) + (c.y + e.y);
        sz += (a.z + b.z) + (c.z + e.z);
        sw += (a.w + b.w) + (c.w + e.w);
    }
    for (; i < end; ++i) {
        float4 a = pr[(size_t)csr[i] * RQ + l];
        sx += a.x; sy += a.y; sz += a.z; sw += a.w;
    }
    const float inv = 1.0f / (float)deg;
    float4* o = reinterpret_cast<float4*>(out) + (size_t)d * RQ + l;
    float4 cur = *o;
    cur.x += sx * inv; cur.y += sy * inv;
    cur.z += sz * inv; cur.w += sw * inv;
    *o = cur;
}

// ============================ launcher =====================================

extern "C" void kernel_launch(void* const* d_in, const int* in_sizes, int n_in,
                              void* d_out, int out_size, void* d_ws, size_t ws_size,
                              hipStream_t stream) {
    const float* x   = (const float*)d_in[0];
    const int*   ei  = (const int*)d_in[1];   // (2, E) int32
    const float* Wl1 = (const float*)d_in[2];
    const float* bl1 = (const float*)d_in[3];
    const float* Wr1 = (const float*)d_in[4];
    const float* Wl2 = (const float*)d_in[5];
    const float* bl2 = (const float*)d_in[6];
    const float* Wr2 = (const float*)d_in[7];
    const float* Wl3 = (const float*)d_in[8];
    const float* bl3 = (const float*)d_in[9];
    const float* Wr3 = (const float*)d_in[10];
    float* out = (float*)d_out;

    const int N = in_sizes[0] / 128;
    const int E = in_sizes[1] / 2;
    const int* src  = ei;
    const int* dstp = ei + E;

    // workspace (bf16 intermediates):
    //   A1 bf16 N*64 | B bf16 N*64 | A2 bf16 N*32 | C bf16 N*32 |
    //   A3 f32 N*20 | rowptr (N+1) | csr (E)
    // transient CSR ints (degi, cursor, bsum) alias A3 (dead before proj3).
    unsigned short* A1 = (unsigned short*)d_ws;
    unsigned short* Bb = A1 + (size_t)N * 64;
    unsigned short* A2 = Bb + (size_t)N * 64;
    unsigned short* Cb = A2 + (size_t)N * 32;
    float* A3 = (float*)(Cb + (size_t)N * 32);
    int* rowptr = (int*)(A3 + (size_t)N * 20);
    int* csr    = rowptr + (N + 1);

    int* degi   = (int*)A3;
    int* cursor = degi + N;
    int* bsum   = cursor + N;

    const int NB = (N + 255) / 256;  // 782 <= 1024 (scan_top limit)

    // --- CSR build ---
    zero_ints<<<NB, 256, 0, stream>>>(degi, N);
    hist_kernel<<<(E + 255) / 256, 256, 0, stream>>>(dstp, degi, E);
    scan_reduce<<<NB, 256, 0, stream>>>(degi, bsum, N);
    scan_top<<<1, 1024, 0, stream>>>(bsum, NB);
    scan_final<<<NB, 256, 0, stream>>>(degi, bsum, rowptr, cursor, N, E);
    fill_kernel<<<(E + 255) / 256, 256, 0, stream>>>(src, dstp, cursor, csr, E);

    // --- layer 1: 128 -> 64 --- fp32 in, bf16 out; LDS-staged x (async DMA)
    // 80 KB LDS (16 W + 64 x-dbuf swizzled), 2 staggered blocks/CU;
    // grid 512 = 256 node-blocks x 2 ch classes, pairs (b, b^8) per XCD.
    proj1_mfma<<<512, 256, 0, stream>>>(x, Wl1, Wr1, bl1, A1, Bb, N);
    agg_bf16<64, 8><<<(int)(((long long)N * 8 + 255) / 256), 256, 0, stream>>>(
        rowptr, csr, A1, Bb, N);

    // --- layer 2: 64 -> 32 --- bf16 in (relu), bf16 out; CH=1, NU=2
    proj_mfma<64, 32, 32, 64, 1, 2, true, true, true><<<1563, 256, 0, stream>>>(
        Bb, Wl2, Wr2, bl2, A2, Cb, N);
    agg_bf16<32, 4><<<(int)(((long long)N * 4 + 255) / 256), 256, 0, stream>>>(
        rowptr, csr, A2, Cb, N);

    // --- layer 3: 32 -> 20 --- bf16 in (relu), fp32 out (p3=A3, r -> d_out)
    proj_mfma<32, 20, 20, 48, 1, 2, true, true, false><<<1563, 256, 0, stream>>>(
        Cb, Wl3, Wr3, bl3, A3, out, N);
    agg_f32<20, 5><<<(int)(((long long)N * 5 + 255) / 256), 256, 0, stream>>>(
        rowptr, csr, A3, out, N);
}

// Round 6
// 333.231 us; speedup vs baseline: 1.0993x; 1.0075x over previous
//
#include <hip/hip_runtime.h>
#include <hip/hip_bf16.h>

// ---------------------------------------------------------------------------
// GraphSAGE 3-layer encoder, fp32 in/out.
//   per layer: h_out = relu?( mean_agg(h)@Wl + b + h@Wr )
// Identity: segment_sum(h[src])@Wl == segment_sum((h@Wl)[src])
//   -> project first (MFMA bf16), aggregate small vectors via CSR gather.
// R12 -> R13:
//   * R12 post-mortem: bigger proj1 tiles neutral (335.7). Cross-round
//     subtraction: non-proj1 dispatches are a stubborn ~283 us and never
//     touched. proj2/proj3 still run the R7/R9 register-prefetch path whose
//     measured ceiling is 2.0-2.3 TB/s (latency-bound serial load->consume).
//   * R13: port proj2/proj3 to the PROVEN proj1 structure (R10/R11):
//     global_load_lds DMA staging of 64-row bf16 x tiles, double-buffered,
//     XOR chunk swizzle c^(r&(CR-1)) on global source + ds_read (rule #21),
//     fragment-order weights in LDS. A-frags are direct ds_read_b128 (input
//     already bf16, no cvt). proj2 CR=8 -> 2-way (free); proj3 CR=4 ->
//     4-way (1.58x, small traffic, acceptable).
//   * zero_ints -> hipMemsetAsync (one less launch, capture-legal).
//   * proj1 / aggs / CSR untouched (isolate the variable).
// ---------------------------------------------------------------------------

typedef __attribute__((ext_vector_type(8))) short short8;
typedef __attribute__((ext_vector_type(4))) float f32x4;

__device__ inline unsigned short f2b(float x) {
    return __bfloat16_as_ushort(__float2bfloat16(x));
}
__device__ inline float b2f(unsigned short u) {
    return __uint_as_float(((unsigned)u) << 16);
}

__device__ __forceinline__ void gload_lds16(const void* g, void* l) {
    __builtin_amdgcn_global_load_lds(
        (const __attribute__((address_space(1))) void*)g,
        (__attribute__((address_space(3))) void*)l, 16, 0, 0);
}

// ============================ CSR construction =============================

__global__ void hist_kernel(const int* __restrict__ dst, int* __restrict__ deg, int E) {
    int i = blockIdx.x * blockDim.x + threadIdx.x;
    if (i < E) atomicAdd(&deg[dst[i]], 1);
}

__global__ void scan_reduce(const int* __restrict__ deg, int* __restrict__ bsum, int n) {
    __shared__ int s[256];
    int i = blockIdx.x * 256 + threadIdx.x;
    s[threadIdx.x] = (i < n) ? deg[i] : 0;
    __syncthreads();
    for (int off = 128; off > 0; off >>= 1) {
        if (threadIdx.x < off) s[threadIdx.x] += s[threadIdx.x + off];
        __syncthreads();
    }
    if (threadIdx.x == 0) bsum[blockIdx.x] = s[0];
}

__global__ void scan_top(int* __restrict__ bsum, int nb) {
    __shared__ int s[1024];
    int t = threadIdx.x;
    int v = (t < nb) ? bsum[t] : 0;
    s[t] = v;
    __syncthreads();
    for (int off = 1; off < 1024; off <<= 1) {
        int add = (t >= off) ? s[t - off] : 0;
        __syncthreads();
        s[t] += add;
        __syncthreads();
    }
    if (t < nb) bsum[t] = s[t] - v;  // exclusive
}

__global__ void scan_final(const int* __restrict__ deg, const int* __restrict__ bsum,
                           int* __restrict__ rowptr, int* __restrict__ cursor,
                           int n, int E) {
    __shared__ int s[256];
    int t = threadIdx.x;
    int i = blockIdx.x * 256 + t;
    int v = (i < n) ? deg[i] : 0;
    s[t] = v;
    __syncthreads();
    for (int off = 1; off < 256; off <<= 1) {
        int add = (t >= off) ? s[t - off] : 0;
        __syncthreads();
        s[t] += add;
        __syncthreads();
    }
    int excl = s[t] - v + bsum[blockIdx.x];
    if (i < n) {
        rowptr[i] = excl;
        cursor[i] = excl;
    }
    if (i == 0) rowptr[n] = E;
}

__global__ void fill_kernel(const int* __restrict__ src, const int* __restrict__ dst,
                            int* __restrict__ cursor, int* __restrict__ csr, int E) {
    int e = blockIdx.x * blockDim.x + threadIdx.x;
    if (e < E) {
        int pos = atomicAdd(&cursor[dst[e]], 1);
        csr[pos] = src[e];
    }
}

// ====================== layer-1 MFMA projection (LDS x) ====================
// 128 -> (64|64). fp32 input. Proven R11/R12 structure: CH=2 block col-split
// (XCD-paired), 16 KB fragment-order weights, 64-row fp32 x tiles dbuf'd via
// global_load_lds with XOR swizzle c^(r&7) (source + read).
// MFMA 16x16x32: A[m=lane&15][k=(lane>>4)*8+i]; D col=lane&15,
// row=(lane>>4)*4+reg (verified R3-R6).

__launch_bounds__(256, 2)
__global__ void proj1_mfma(const float* __restrict__ x,
                           const float* __restrict__ Wl,
                           const float* __restrict__ Wr,
                           const float* __restrict__ bl,
                           unsigned short* __restrict__ pv,
                           unsigned short* __restrict__ rv,
                           int n) {
    constexpr int S = 4;             // k-steps (128/32)
    constexpr int TWB = 4;           // weight col-tiles staged per block
    constexpr int NCH = TWB * S * 64;

    __shared__ __attribute__((aligned(16))) unsigned short sW[NCH * 8];   // 16 KB
    __shared__ __attribute__((aligned(16))) float sX[2][64 * 128];        // 2 x 32 KB

    const int b = (int)blockIdx.x;
    const int ch = (b >> 3) & 1;
    const int blk = (b & 7) | ((b >> 4) << 3);
    const int nblk = (int)gridDim.x >> 1;

    const int tid = threadIdx.x;
    // stage this block's ch-half of weights as lane-ordered fragments
    for (int chunk = tid; chunk < NCH; chunk += 256) {
        const int lane_c = chunk & 63;
        const int rest = chunk >> 6;         // t*S + s
        const int s = rest % S;
        const int t = rest / S;
        const int c = (ch * TWB + t) * 16 + (lane_c & 15);
        const int k0 = s * 32 + (lane_c >> 4) * 8;
        short8 pack;
#pragma unroll
        for (int j = 0; j < 8; ++j) {
            const int k = k0 + j;
            float w = (c < 64) ? Wl[k * 64 + c] : Wr[k * 64 + (c - 64)];
            pack[j] = (short)f2b(w);
        }
        *reinterpret_cast<short8*>(&sW[(size_t)chunk * 8]) = pack;
    }

    const int wave = tid >> 6, lane = tid & 63;
    const int rg = wave;                     // row-group 0..3
    const int q = lane >> 4, ln = lane & 15;

    int colg[4];
    float bias[4];
#pragma unroll
    for (int t = 0; t < 4; ++t) {
        colg[t] = ch * 64 + t * 16 + ln;
        bias[t] = (colg[t] >= 64) ? bl[colg[t] - 64] : 0.0f;
    }

    // async-stage one 64-row x tile into sX[d] (2048 x 16B chunks).
    // LDS slot ci holds global chunk (row = ci>>5, col = (ci&31) ^ (row&7)).
    auto stage = [&](int d, int nb) {
#pragma unroll
        for (int i = 0; i < 8; ++i) {
            const int cbase = wave * 512 + i * 64;       // wave-uniform
            const int ci = cbase + lane;
            const int rl = ci >> 5;                      // local row 0..63
            const int cc = ci & 31;                      // swizzled slot col
            int row = nb + rl;
            if (row >= n) row = n - 1;                   // clamp (stores guarded)
            const float* g = x + (size_t)row * 128 + (size_t)((cc ^ (rl & 7)) << 2);
            char* l = (char*)&sX[d][0] + (size_t)cbase * 16;
            gload_lds16(g, l);
        }
    };

    auto compute = [&](int d, int nb) {
        const int rowb = nb + rg * 16;
        const int rl = rg * 16 + ln;                     // local row
        const int swz = rl & 7;
        const float* xbase = &sX[d][(size_t)rl * 128];
        f32x4 acc[4];
#pragma unroll
        for (int t = 0; t < 4; ++t) acc[t] = (f32x4){0.f, 0.f, 0.f, 0.f};
#pragma unroll
        for (int s = 0; s < S; ++s) {
            const int c0 = s * 8 + q * 2;                // 16B chunk col
            float4 v0 = *reinterpret_cast<const float4*>(xbase + ((c0 ^ swz) << 2));
            float4 v1 = *reinterpret_cast<const float4*>(xbase + (((c0 + 1) ^ swz) << 2));
            short8 a;
            a[0] = (short)f2b(v0.x); a[1] = (short)f2b(v0.y);
            a[2] = (short)f2b(v0.z); a[3] = (short)f2b(v0.w);
            a[4] = (short)f2b(v1.x); a[5] = (short)f2b(v1.y);
            a[6] = (short)f2b(v1.z); a[7] = (short)f2b(v1.w);
#pragma unroll
            for (int t = 0; t < 4; ++t) {
                short8 bf = *reinterpret_cast<const short8*>(
                    &sW[((size_t)(t * S + s)) * 512 + (size_t)lane * 8]);
                acc[t] = __builtin_amdgcn_mfma_f32_16x16x32_bf16(a, bf, acc[t], 0, 0, 0);
            }
        }
#pragma unroll
        for (int t = 0; t < 4; ++t) {
            const int c = colg[t];
#pragma unroll
            for (int rr = 0; rr < 4; ++rr) {
                const int row = rowb + q * 4 + rr;
                if (row < n) {
                    if (c < 64)
                        pv[(size_t)row * 64 + c] = f2b(acc[t][rr]);
                    else
                        rv[(size_t)row * 64 + (c - 64)] = f2b(acc[t][rr] + bias[t]);
                }
            }
        }
    };

    constexpr int npi = 64;
    const int stride = nblk * npi;
    int nb = blk * npi;
    if (nb >= n) return;
    stage(0, nb);
    __syncthreads();          // weights + tile0 ready
    while (true) {
        const int nb1 = nb + stride;
        if (nb1 < n) stage(1, nb1);
        compute(0, nb);
        __syncthreads();      // tile1 arrived; sX[0] free
        if (nb1 >= n) break;
        const int nb2 = nb1 + stride;
        if (nb2 < n) stage(0, nb2);
        compute(1, nb1);
        __syncthreads();
        nb = nb2;
        if (nb >= n) break;
    }
}

// ================= layers 2/3 MFMA projection (LDS-DMA, bf16 in) ==========
// Same structure as proj1 but bf16 input rows (no cvt: A-frag is a direct
// swizzled ds_read_b128) and CH=1 (weights tiny). CR = DIN/8 16B chunks per
// row; swizzle mask CR-1. 64-row tiles, double-buffered.

template <int DIN, int DP, int DR, int DT2, bool RELU, bool OUT_BF16>
__launch_bounds__(256, 4)
__global__ void proj_lds(const unsigned short* __restrict__ xv,
                         const float* __restrict__ Wl,
                         const float* __restrict__ Wr,
                         const float* __restrict__ bl,
                         void* __restrict__ pv,
                         void* __restrict__ rv,
                         int n) {
    constexpr int S = DIN / 32;              // MFMA k-steps
    constexpr int TILES = DT2 / 16;          // col tiles (all owned per block)
    constexpr int CR = DIN / 8;              // 16B chunks per bf16 row
    constexpr int NCH = TILES * S * 64;      // weight fragment chunks

    __shared__ __attribute__((aligned(16))) unsigned short sW[NCH * 8];
    __shared__ __attribute__((aligned(16))) unsigned short sX[2][64 * DIN];

    const int blk = (int)blockIdx.x;
    const int nblk = (int)gridDim.x;
    const int tid = threadIdx.x;

    // stage weights as lane-ordered fragments (proven R6 layout)
    for (int chunk = tid; chunk < NCH; chunk += 256) {
        const int lane_c = chunk & 63;
        const int rest = chunk >> 6;         // t*S + s
        const int s = rest % S;
        const int t = rest / S;
        const int c = t * 16 + (lane_c & 15);
        const int k0 = s * 32 + (lane_c >> 4) * 8;
        short8 pack;
#pragma unroll
        for (int j = 0; j < 8; ++j) {
            float w = 0.f;
            const int k = k0 + j;
            if (c < DP) w = Wl[k * DP + c];
            else if (c < DP + DR) w = Wr[k * DR + (c - DP)];
            pack[j] = (short)f2b(w);
        }
        *reinterpret_cast<short8*>(&sW[(size_t)chunk * 8]) = pack;
    }

    const int wave = tid >> 6, lane = tid & 63;
    const int rg = wave;                     // row-group 0..3
    const int q = lane >> 4, ln = lane & 15;

    int colg[TILES];
    float bias[TILES];
#pragma unroll
    for (int t = 0; t < TILES; ++t) {
        colg[t] = t * 16 + ln;
        bias[t] = (colg[t] >= DP && colg[t] < DP + DR) ? bl[colg[t] - DP] : 0.0f;
    }

    // async-stage one 64-row bf16 tile (64*CR chunks); slot ci holds global
    // chunk (row = ci/CR, col = (ci%CR) ^ (row & (CR-1))).
    auto stage = [&](int d, int nb) {
#pragma unroll
        for (int i = 0; i < CR / 4; ++i) {
            const int cbase = wave * (16 * CR) + i * 64; // wave-uniform
            const int ci = cbase + lane;
            const int rl = ci / CR;                      // local row 0..63
            const int cc = ci & (CR - 1);                // swizzled slot col
            int row = nb + rl;
            if (row >= n) row = n - 1;                   // clamp (stores guarded)
            const unsigned short* g =
                xv + (size_t)row * DIN + (size_t)((cc ^ (rl & (CR - 1))) << 3);
            char* l = (char*)&sX[d][0] + (size_t)cbase * 16;
            gload_lds16(g, l);
        }
    };

    auto compute = [&](int d, int nb) {
        const int rl = rg * 16 + ln;                     // local row
        const int swz = rl & (CR - 1);
        const unsigned short* rowb = &sX[d][(size_t)rl * DIN];
        f32x4 acc[TILES];
#pragma unroll
        for (int t = 0; t < TILES; ++t) acc[t] = (f32x4){0.f, 0.f, 0.f, 0.f};
#pragma unroll
        for (int s = 0; s < S; ++s) {
            const int c0 = s * 4 + q;                    // 16B chunk col
            short8 a = *reinterpret_cast<const short8*>(rowb + (size_t)((c0 ^ swz) << 3));
            if (RELU) {
#pragma unroll
                for (int j = 0; j < 8; ++j)
                    a[j] = ((short)a[j] < 0) ? (short)0 : a[j];
            }
#pragma unroll
            for (int t = 0; t < TILES; ++t) {
                short8 bf = *reinterpret_cast<const short8*>(
                    &sW[((size_t)(t * S + s)) * 512 + (size_t)lane * 8]);
                acc[t] = __builtin_amdgcn_mfma_f32_16x16x32_bf16(a, bf, acc[t], 0, 0, 0);
            }
        }
        const int rowbase = nb + rg * 16 + q * 4;
#pragma unroll
        for (int t = 0; t < TILES; ++t) {
            const int c = colg[t];
#pragma unroll
            for (int rr = 0; rr < 4; ++rr) {
                const int row = rowbase + rr;
                if (row < n) {
                    if (c < DP) {
                        if constexpr (OUT_BF16)
                            ((unsigned short*)pv)[(size_t)row * DP + c] = f2b(acc[t][rr]);
                        else
                            ((float*)pv)[(size_t)row * DP + c] = acc[t][rr];
                    } else if (c < DP + DR) {
                        const float v = acc[t][rr] + bias[t];
                        if constexpr (OUT_BF16)
                            ((unsigned short*)rv)[(size_t)row * DR + (c - DP)] = f2b(v);
                        else
                            ((float*)rv)[(size_t)row * DR + (c - DP)] = v;
                    }
                }
            }
        }
    };

    constexpr int npi = 64;
    const int stride = nblk * npi;
    int nb = blk * npi;
    if (nb >= n) return;
    stage(0, nb);
    __syncthreads();          // weights + tile0 ready
    while (true) {
        const int nb1 = nb + stride;
        if (nb1 < n) stage(1, nb1);
        compute(0, nb);
        __syncthreads();      // tile1 arrived; sX[0] free
        if (nb1 >= n) break;
        const int nb2 = nb1 + stride;
        if (nb2 < n) stage(0, nb2);
        compute(1, nb1);
        __syncthreads();
        nb = nb2;
        if (nb >= n) break;
    }
}

// ============================ aggregation ==================================
// out[d] += mean over csr row of p rows. bf16 buffers: L=D/8 lanes per node,
// one short8 per lane per gathered row; fp32 accumulation; unroll-4 keeps
// 4 independent csr->row chains in flight.

template <int D, int L>
__global__ void agg_bf16(const int* __restrict__ rowptr,
                         const int* __restrict__ csr,
                         const unsigned short* __restrict__ p,
                         unsigned short* __restrict__ out,
                         int n) {
    constexpr int RQ = D / 8;            // short8s per row
    long long gid = (long long)blockIdx.x * blockDim.x + threadIdx.x;
    int d = (int)(gid / L);
    int l = (int)(gid % L);
    if (d >= n) return;
    int beg = rowptr[d], end = rowptr[d + 1];
    int deg = end - beg;
    if (deg <= 0) return;

    const short8* pr = reinterpret_cast<const short8*>(p);
    float s[8];
#pragma unroll
    for (int j = 0; j < 8; ++j) s[j] = 0.0f;

    int i = beg;
    for (; i + 4 <= end; i += 4) {
        int e0 = csr[i], e1 = csr[i + 1], e2 = csr[i + 2], e3 = csr[i + 3];
        short8 a = pr[(size_t)e0 * RQ + l];
        short8 b = pr[(size_t)e1 * RQ + l];
        short8 c = pr[(size_t)e2 * RQ + l];
        short8 e = pr[(size_t)e3 * RQ + l];
#pragma unroll
        for (int j = 0; j < 8; ++j)
            s[j] += (b2f((unsigned short)a[j]) + b2f((unsigned short)b[j])) +
                    (b2f((unsigned short)c[j]) + b2f((unsigned short)e[j]));
    }
    for (; i < end; ++i) {
        short8 a = pr[(size_t)csr[i] * RQ + l];
#pragma unroll
        for (int j = 0; j < 8; ++j) s[j] += b2f((unsigned short)a[j]);
    }

    const float inv = 1.0f / (float)deg;
    short8* o = reinterpret_cast<short8*>(out) + (size_t)d * RQ + l;
    short8 cur = *o;
#pragma unroll
    for (int j = 0; j < 8; ++j) {
        float v = b2f((unsigned short)cur[j]) + s[j] * inv;
        cur[j] = (short)f2b(v);
    }
    *o = cur;
}

// fp32 variant for the final layer (out = d_out, fp32); L lanes per node,
// one float4 per lane (L == D/4, all lanes active).
template <int D, int L>
__global__ void agg_f32(const int* __restrict__ rowptr,
                        const int* __restrict__ csr,
                        const float* __restrict__ p,
                        float* __restrict__ out,
                        int n) {
    constexpr int RQ = D / 4;            // float4s per row
    static_assert(L == RQ, "agg_f32: one float4 per lane");
    long long gid = (long long)blockIdx.x * blockDim.x + threadIdx.x;
    int d = (int)(gid / L);
    int l = (int)(gid % L);
    if (d >= n) return;
    int beg = rowptr[d], end = rowptr[d + 1];
    int deg = end - beg;
    if (deg <= 0) return;

    const float4* pr = reinterpret_cast<const float4*>(p);
    float sx = 0.f, sy = 0.f, sz = 0.f, sw = 0.f;
    int i = beg;
    for (; i + 4 <= end; i += 4) {
        int s0 = csr[i], s1 = csr[i + 1], s2 = csr[i + 2], s3 = csr[i + 3];
        float4 a = pr[(size_t)s0 * RQ + l];
        float4 b = pr[(size_t)s1 * RQ + l];
        float4 c = pr[(size_t)s2 * RQ + l];
        float4 e = pr[(size_t)s3 * RQ + l];
        sx += (a.x + b.x) + (c.x + e.x);
        sy += (a.y + b.y) + (c.y + e.y);
        sz += (a.z + b.z) + (c.z + e.z);
        sw += (a.w + b.w) + (c.w + e.w);
    }
    for (; i < end; ++i) {
        float4 a = pr[(size_t)csr[i] * RQ + l];
        sx += a.x; sy += a.y; sz += a.z; sw += a.w;
    }
    const float inv = 1.0f / (float)deg;
    float4* o = reinterpret_cast<float4*>(out) + (size_t)d * RQ + l;
    float4 cur = *o;
    cur.x += sx * inv; cur.y += sy * inv;
    cur.z += sz * inv; cur.w += sw * inv;
    *o = cur;
}

// ============================ launcher =====================================

extern "C" void kernel_launch(void* const* d_in, const int* in_sizes, int n_in,
                              void* d_out, int out_size, void* d_ws, size_t ws_size,
                              hipStream_t stream) {
    const float* x   = (const float*)d_in[0];
    const int*   ei  = (const int*)d_in[1];   // (2, E) int32
    const float* Wl1 = (const float*)d_in[2];
    const float* bl1 = (const float*)d_in[3];
    const float* Wr1 = (const float*)d_in[4];
    const float* Wl2 = (const float*)d_in[5];
    const float* bl2 = (const float*)d_in[6];
    const float* Wr2 = (const float*)d_in[7];
    const float* Wl3 = (const float*)d_in[8];
    const float* bl3 = (const float*)d_in[9];
    const float* Wr3 = (const float*)d_in[10];
    float* out = (float*)d_out;

    const int N = in_sizes[0] / 128;
    const int E = in_sizes[1] / 2;
    const int* src  = ei;
    const int* dstp = ei + E;

    // workspace (bf16 intermediates):
    //   A1 bf16 N*64 | B bf16 N*64 | A2 bf16 N*32 | C bf16 N*32 |
    //   A3 f32 N*20 | rowptr (N+1) | csr (E)
    // transient CSR ints (degi, cursor, bsum) alias A3 (dead before proj3).
    unsigned short* A1 = (unsigned short*)d_ws;
    unsigned short* Bb = A1 + (size_t)N * 64;
    unsigned short* A2 = Bb + (size_t)N * 64;
    unsigned short* Cb = A2 + (size_t)N * 32;
    float* A3 = (float*)(Cb + (size_t)N * 32);
    int* rowptr = (int*)(A3 + (size_t)N * 20);
    int* csr    = rowptr + (N + 1);

    int* degi   = (int*)A3;
    int* cursor = degi + N;
    int* bsum   = cursor + N;

    const int NB = (N + 255) / 256;  // 782 <= 1024 (scan_top limit)

    // --- CSR build ---
    hipMemsetAsync(degi, 0, (size_t)N * sizeof(int), stream);
    hist_kernel<<<(E + 255) / 256, 256, 0, stream>>>(dstp, degi, E);
    scan_reduce<<<NB, 256, 0, stream>>>(degi, bsum, N);
    scan_top<<<1, 1024, 0, stream>>>(bsum, NB);
    scan_final<<<NB, 256, 0, stream>>>(degi, bsum, rowptr, cursor, N, E);
    fill_kernel<<<(E + 255) / 256, 256, 0, stream>>>(src, dstp, cursor, csr, E);

    // --- layer 1: 128 -> 64 --- fp32 in, bf16 out; LDS-staged x (async DMA)
    // 80 KB LDS (16 W + 64 x-dbuf swizzled), 2 blocks/CU; grid 512 =
    // 256 node-blocks x 2 ch classes, pairs (b, b^8) per XCD.
    proj1_mfma<<<512, 256, 0, stream>>>(x, Wl1, Wr1, bl1, A1, Bb, N);
    agg_bf16<64, 8><<<(int)(((long long)N * 8 + 255) / 256), 256, 0, stream>>>(
        rowptr, csr, A1, Bb, N);

    // --- layer 2: 64 -> 32 --- bf16 in (relu), bf16 out; LDS-DMA path
    // 24 KB LDS (8 W + 16 x-dbuf), grid 1024 (~3 trips)
    proj_lds<64, 32, 32, 64, true, true><<<1024, 256, 0, stream>>>(
        Bb, Wl2, Wr2, bl2, A2, Cb, N);
    agg_bf16<32, 4><<<(int)(((long long)N * 4 + 255) / 256), 256, 0, stream>>>(
        rowptr, csr, A2, Cb, N);

    // --- layer 3: 32 -> 20 --- bf16 in (relu), fp32 out (p3=A3, r -> d_out)
    // 11 KB LDS (3 W + 8 x-dbuf), grid 1024
    proj_lds<32, 20, 20, 48, true, false><<<1024, 256, 0, stream>>>(
        Cb, Wl3, Wr3, bl3, A3, out, N);
    agg_f32<20, 5><<<(int)(((long long)N * 5 + 255) / 256), 256, 0, stream>>>(
        rowptr, csr, A3, out, N);
}